// Round 6
// baseline (1054.846 us; speedup 1.0000x reference)
//
#include <hip/hip_runtime.h>
#include <stdint.h>

#define N_NODES 100000
#define N_EDGES 3200000
#define IN_DIM 128
#define HID 64
#define N_GRAPHS 64
#define BN_EPS 1e-5f
#define NSHARD 16
#define BUCK_SH 7
#define BUCK_SZ 128
#define NBUCK ((N_NODES + BUCK_SZ - 1) / BUCK_SZ)   // 782
#define NCNT (NBUCK * 8)                             // 6256
#define NCHUNK (N_EDGES / 4)                         // 800000
#define BIN_GRID (NCHUNK / 256)                      // 3125 blocks, 1 chunk/thread
#define EDGE_CAP 6016                                // LDS edge stage (mean 4092)

// __builtin_nontemporal_load needs native (ext_vector) types, not HIP structs.
typedef float vf4 __attribute__((ext_vector_type(4)));
typedef int   vi4 __attribute__((ext_vector_type(4)));
typedef unsigned vu2 __attribute__((ext_vector_type(2)));

__device__ __forceinline__ float4 nt_f4(const float* p) {
    vf4 v = __builtin_nontemporal_load((const vf4*)p);
    return make_float4(v.x, v.y, v.z, v.w);
}
__device__ __forceinline__ int4 nt_i4(const int* p) {
    vi4 v = __builtin_nontemporal_load((const vi4*)p);
    return make_int4(v.x, v.y, v.z, v.w);
}
__device__ __forceinline__ uint2 nt_u2(const uint2* p) {
    vu2 v = __builtin_nontemporal_load((const vu2*)p);
    return make_uint2(v.x, v.y);
}
__device__ __forceinline__ float nt_f(const float* p) {
    return __builtin_nontemporal_load(p);
}

// ---------------------------------------------------------------------------
// count edges per (bucket, sub-stream). chunk ch covers edges 4ch..4ch+3;
// s=(ch>>8)&7 == blockIdx&7 == XCD id -> cursor regions are XCD-local.
__global__ void k_count(const int* __restrict__ ei, int* __restrict__ cnt2) {
    int stride = gridDim.x * blockDim.x;
    for (int ch = blockIdx.x * blockDim.x + threadIdx.x; ch < NCHUNK; ch += stride) {
        int4 c4 = nt_i4(ei + N_EDGES + 4 * ch);
        int s = (ch >> 8) & 7;
        atomicAdd(&cnt2[((c4.x >> BUCK_SH) << 3) + s], 1);
        atomicAdd(&cnt2[((c4.y >> BUCK_SH) << 3) + s], 1);
        atomicAdd(&cnt2[((c4.z >> BUCK_SH) << 3) + s], 1);
        atomicAdd(&cnt2[((c4.w >> BUCK_SH) << 3) + s], 1);
    }
}

// single-block exclusive scan of cnt2[6256] -> soff[6257]; init cursors; nptr tail
__global__ void k_scan6k(const int* __restrict__ cnt2, int* __restrict__ soff,
                         int* __restrict__ cur, int* __restrict__ nptr) {
    __shared__ int parts[256];
    int t = threadIdx.x;
    int s = 0;
    for (int i = 0; i < 25; ++i) {
        int idx = t * 25 + i;
        if (idx < NCNT) s += cnt2[idx];
    }
    parts[t] = s;
    __syncthreads();
    for (int off = 1; off < 256; off <<= 1) {
        int x = (t >= off) ? parts[t - off] : 0;
        __syncthreads();
        parts[t] += x;
        __syncthreads();
    }
    int run = (t > 0) ? parts[t - 1] : 0;
    for (int i = 0; i < 25; ++i) {
        int idx = t * 25 + i;
        if (idx < NCNT) {
            soff[idx] = run;
            cur[idx] = run;
            run += cnt2[idx];
        }
    }
    if (t == 255) soff[NCNT] = parts[255];
    if (t == 0) nptr[N_NODES] = N_EDGES;
}

// bin edges into bucket-substream regions + fused weighted degree atomics.
// ebuf[p] = {r | (c_local<<17), w}; deg[c] += w (self-loop +1 added in k_dinv)
__global__ void k_bin(const int* __restrict__ ei, const float* __restrict__ ew,
                      int* __restrict__ cur, uint2* __restrict__ ebuf,
                      float* __restrict__ deg) {
    int stride = gridDim.x * blockDim.x;
    for (int ch = blockIdx.x * blockDim.x + threadIdx.x; ch < NCHUNK; ch += stride) {
        int4 r4 = nt_i4(ei + 4 * ch);
        int4 c4 = nt_i4(ei + N_EDGES + 4 * ch);
        float4 w4 = nt_f4(ew + 4 * ch);
        int s = (ch >> 8) & 7;
        int rr[4] = {r4.x, r4.y, r4.z, r4.w};
        int cc[4] = {c4.x, c4.y, c4.z, c4.w};
        float ww[4] = {w4.x, w4.y, w4.z, w4.w};
#pragma unroll
        for (int u = 0; u < 4; ++u) {
            int p = atomicAdd(&cur[((cc[u] >> BUCK_SH) << 3) + s], 1);
            ebuf[p] = make_uint2((unsigned)(rr[u] | ((cc[u] & (BUCK_SZ - 1)) << 17)),
                                 __float_as_uint(ww[u]));
            atomicAdd(&deg[cc[u]], ww[u]);
        }
    }
}

// dinv = rsqrt(deg + 1) — global sync point so k_sortnorm can read any dinv[r]
__global__ void k_dinv(const float* __restrict__ deg, float* __restrict__ dinv) {
    int i = blockIdx.x * blockDim.x + threadIdx.x;
    if (i < N_NODES) dinv[i] = rsqrtf(deg[i] + 1.0f);
}

// ---------------------------------------------------------------------------
// per-bucket counting sort by local dest + norm. Stages edges in LDS (one
// global read pass). dinv fully computed before this launches (no race).
__global__ __launch_bounds__(256) void k_sortnorm(const uint2* __restrict__ ebuf,
                                                  const int* __restrict__ soff,
                                                  const float* __restrict__ dinv,
                                                  uint2* __restrict__ ebuf2,
                                                  int* __restrict__ nptr) {
    __shared__ uint2 se[EDGE_CAP];
    __shared__ float sdi[BUCK_SZ];
    __shared__ int scnt[BUCK_SZ];
    __shared__ int scur[BUCK_SZ];
    int b = blockIdx.x, t = threadIdx.x;
    if (t < BUCK_SZ) {
        scnt[t] = 0;
        int node = b * BUCK_SZ + t;
        sdi[t] = (node < N_NODES) ? dinv[node] : 0.f;
    }
    __syncthreads();
    int beg = soff[b << 3], end = soff[(b << 3) + 8];
    int n = end - beg;
    bool fit = (n <= EDGE_CAP);
    // pass 1: stage edges + dest histogram
    for (int i = t; i < n; i += 256) {
        uint2 u = nt_u2(ebuf + beg + i);
        if (fit) se[i] = u;
        atomicAdd(&scnt[u.x >> 17], 1);
    }
    __syncthreads();
    // inclusive scan over 128 counts (all 256 threads hit barriers)
    for (int off = 1; off < BUCK_SZ; off <<= 1) {
        int x = 0;
        if (t < BUCK_SZ && t >= off) x = scnt[t - off];
        __syncthreads();
        if (t < BUCK_SZ) scnt[t] += x;
        __syncthreads();
    }
    if (t < BUCK_SZ) {
        int excl = (t > 0) ? scnt[t - 1] : 0;
        scur[t] = beg + excl;
        int node = b * BUCK_SZ + t;
        if (node < N_NODES) nptr[node] = beg + excl;
    }
    __syncthreads();
    // pass 2: scatter within bucket (L2/L3-resident window) + norm
    for (int i = t; i < n; i += 256) {
        uint2 u = fit ? se[i] : nt_u2(ebuf + beg + i);
        int r = u.x & 131071;
        int cl = u.x >> 17;
        float nm = dinv[r] * __uint_as_float(u.y) * sdi[cl];
        int p = atomicAdd(&scur[cl], 1);
        ebuf2[p] = make_uint2((unsigned)r, __float_as_uint(nm));
    }
}

// ---------------------------------------------------------------------------
// GEMM: out[n][c] = sum_k in[n][k] * W[k][c], optional fused BN+ReLU on input
template <int K, bool BN>
__global__ __launch_bounds__(256) void k_gemm(const float* __restrict__ in,
                                              const float* __restrict__ W,
                                              const float* __restrict__ scale,
                                              const float* __restrict__ shift,
                                              float* __restrict__ out) {
    __shared__ float ws[K * 64];
    __shared__ float xs[32 * 132];
    __shared__ float ssc[64], ssh[64];
    int t = threadIdx.x;
    int nbase = blockIdx.x * 128;

#pragma unroll
    for (int i = 0; i < K / 16; ++i) {
        int idx = t + 256 * i;
        ((float4*)ws)[idx] = ((const float4*)W)[idx];
    }
    if (BN && t < 64) { ssc[t] = scale[t]; ssh[t] = shift[t]; }

    int cg = t & 15;
    int ng = t >> 4;
    float acc[8][4];
#pragma unroll
    for (int i = 0; i < 8; ++i)
#pragma unroll
        for (int j = 0; j < 4; ++j) acc[i][j] = 0.f;

    for (int k0 = 0; k0 < K; k0 += 32) {
        __syncthreads();
#pragma unroll
        for (int i = 0; i < 4; ++i) {
            int idx = t + 256 * i;
            int row = idx >> 3;
            int kq = idx & 7;
            int node = nbase + row;
            float4 v = make_float4(0.f, 0.f, 0.f, 0.f);
            if (node < N_NODES)
                v = nt_f4(in + (size_t)node * K + k0 + kq * 4);
            float vv[4] = {v.x, v.y, v.z, v.w};
#pragma unroll
            for (int u = 0; u < 4; ++u) {
                float val = vv[u];
                if (BN) {
                    int k = k0 + kq * 4 + u;
                    val = fmaxf(ssc[k] * val + ssh[k], 0.f);
                }
                xs[(kq * 4 + u) * 132 + row] = val;
            }
        }
        __syncthreads();
#pragma unroll
        for (int k = 0; k < 32; ++k) {
            float4 wv = *(const float4*)(ws + (k0 + k) * 64 + cg * 4);
            float4 xa = *(const float4*)(xs + k * 132 + ng * 8);
            float4 xb = *(const float4*)(xs + k * 132 + ng * 8 + 4);
            float xv[8] = {xa.x, xa.y, xa.z, xa.w, xb.x, xb.y, xb.z, xb.w};
            float wvv[4] = {wv.x, wv.y, wv.z, wv.w};
#pragma unroll
            for (int i = 0; i < 8; ++i)
#pragma unroll
                for (int j = 0; j < 4; ++j) acc[i][j] += xv[i] * wvv[j];
        }
    }
#pragma unroll
    for (int i = 0; i < 8; ++i) {
        int node = nbase + ng * 8 + i;
        if (node < N_NODES) {
            float4 o4 = make_float4(acc[i][0], acc[i][1], acc[i][2], acc[i][3]);
            *(float4*)(out + (size_t)node * 64 + cg * 4) = o4;
        }
    }
}

// ---------------------------------------------------------------------------
// CSR gather-aggregation: wave per node (lane=channel), register accumulation,
// explicit 8-deep load pipelining for MLP. Fused self-loop, bias, BN partials.
__global__ __launch_bounds__(256) void k_agg(const float* __restrict__ hin,
                                             const uint2* __restrict__ ebuf2,
                                             const int* __restrict__ nptr,
                                             const float* __restrict__ dinv,
                                             const float* __restrict__ bias,
                                             float* __restrict__ hout,
                                             float* __restrict__ bn_shard) {
    int wave = threadIdx.x >> 6;
    int lane = threadIdx.x & 63;
    float s = 0.f, q = 0.f;
    float bl = bias[lane];
    int vbase = blockIdx.x * 32 + wave * 8;
    for (int vi = 0; vi < 8; ++vi) {
        int v = vbase + vi;
        if (v >= N_NODES) break;
        int beg = nptr[v], end = nptr[v + 1];
        float acc = 0.f;
        int j = beg;
        for (; j + 8 <= end; j += 8) {
            float fv[8], fn[8];
#pragma unroll
            for (int u = 0; u < 8; ++u) {
                uint2 e = nt_u2(ebuf2 + j + u);
                fn[u] = __uint_as_float(e.y);
                fv[u] = hin[((size_t)e.x << 6) + lane];
            }
#pragma unroll
            for (int u = 0; u < 8; ++u) acc = fmaf(fn[u], fv[u], acc);
        }
        for (; j < end; ++j) {
            uint2 e = nt_u2(ebuf2 + j);
            acc = fmaf(__uint_as_float(e.y), hin[((size_t)e.x << 6) + lane], acc);
        }
        float dv = dinv[v];
        acc = fmaf(dv * dv, hin[((size_t)v << 6) + lane], acc);
        acc += bl;
        hout[((size_t)v << 6) + lane] = acc;
        s += acc;
        q += acc * acc;
    }
    __shared__ float sm[4][64], qm[4][64];
    sm[wave][lane] = s;
    qm[wave][lane] = q;
    __syncthreads();
    if (wave == 0) {
        float ts = sm[0][lane] + sm[1][lane] + sm[2][lane] + sm[3][lane];
        float tq = qm[0][lane] + qm[1][lane] + qm[2][lane] + qm[3][lane];
        float* shard = bn_shard + (blockIdx.x & (NSHARD - 1)) * 128;
        atomicAdd(&shard[lane], ts);
        atomicAdd(&shard[64 + lane], tq);
    }
}

// reduce BN shards -> scale/shift; re-zero shards for the next layer
__global__ void k_bn_final(float* __restrict__ bn_shard, const float* __restrict__ gamma,
                           const float* __restrict__ beta, float* __restrict__ scale,
                           float* __restrict__ shift) {
    int t = threadIdx.x;
    if (t < 64) {
        float s = 0.f, q = 0.f;
        for (int i = 0; i < NSHARD; ++i) {
            s += bn_shard[i * 128 + t];
            q += bn_shard[i * 128 + 64 + t];
        }
        float mean = s * (1.0f / N_NODES);
        float var = q * (1.0f / N_NODES) - mean * mean;
        float sc = gamma[t] * rsqrtf(var + BN_EPS);
        scale[t] = sc;
        shift[t] = beta[t] - mean * sc;
    }
    __syncthreads();
    for (int i = t; i < NSHARD * 128; i += 256) bn_shard[i] = 0.f;
}

// ---------------------------------------------------------------------------
__global__ __launch_bounds__(256) void k_pool(const float* __restrict__ a2,
                                              const float* __restrict__ scale,
                                              const float* __restrict__ shift,
                                              const int* __restrict__ batch,
                                              float* __restrict__ pooled,
                                              float* __restrict__ pcnt) {
    int t = threadIdx.x;
    int c = t & 63;
    int rg = t >> 6;
    int base = blockIdx.x * 1024;
    float sc = scale[c], sh = shift[c];
    int gcur = -1;
    float acc = 0.f, cacc = 0.f;
    for (int i = rg; i < 1024; i += 4) {
        int v = base + i;
        if (v >= N_NODES) break;
        int g = batch[v];
        if (g != gcur) {
            if (gcur >= 0) {
                atomicAdd(&pooled[gcur * 64 + c], acc);
                if (c == 0) atomicAdd(&pcnt[gcur], cacc);
            }
            gcur = g;
            acc = 0.f;
            cacc = 0.f;
        }
        float h = fmaxf(sc * nt_f(a2 + (size_t)v * 64 + c) + sh, 0.f);
        acc += h;
        cacc += 1.f;
    }
    if (gcur >= 0) {
        atomicAdd(&pooled[gcur * 64 + c], acc);
        if (c == 0) atomicAdd(&pcnt[gcur], cacc);
    }
}

__global__ void k_out(const float* __restrict__ pooled, const float* __restrict__ pcnt,
                      const float* __restrict__ Wout, const float* __restrict__ bout,
                      float* __restrict__ out) {
    int g = threadIdx.x;
    if (g < N_GRAPHS) {
        float cnt = fmaxf(pcnt[g], 1.0f);
        float s = 0.f;
        for (int c = 0; c < 64; ++c) s += pooled[g * 64 + c] * Wout[c];
        out[g] = s / cnt + bout[0];
    }
}

// ---------------------------------------------------------------------------
extern "C" void kernel_launch(void* const* d_in, const int* in_sizes, int n_in,
                              void* d_out, int out_size, void* d_ws, size_t ws_size,
                              hipStream_t stream) {
    const float* x    = (const float*)d_in[0];
    const int*   ei   = (const int*)d_in[1];
    const float* ew   = (const float*)d_in[2];
    const int*   batch= (const int*)d_in[3];
    const float* W1   = (const float*)d_in[4];
    const float* b1   = (const float*)d_in[5];
    const float* W2   = (const float*)d_in[6];
    const float* b2   = (const float*)d_in[7];
    const float* g1   = (const float*)d_in[8];
    const float* be1  = (const float*)d_in[9];
    const float* g2   = (const float*)d_in[10];
    const float* be2  = (const float*)d_in[11];
    const float* Wout = (const float*)d_in[12];
    const float* bout = (const float*)d_in[13];
    float* out = (float*)d_out;

    char* w = (char*)d_ws;
    size_t o = 0;
    auto alloc = [&](size_t bytes) -> void* {
        void* p = w + o;
        o = (o + bytes + 255) & ~(size_t)255;
        return p;
    };
    int*   cnt2    = (int*)alloc(NCNT * 4);
    int*   soff    = (int*)alloc((NCNT + 1) * 4);
    int*   cur     = (int*)alloc(NCNT * 4);
    int*   nptr    = (int*)alloc((N_NODES + 1) * 4);
    float* deg     = (float*)alloc(N_NODES * 4);
    float* dinv    = (float*)alloc(N_NODES * 4);
    float* bnshard = (float*)alloc(NSHARD * 128 * 4);
    float* scale1  = (float*)alloc(64 * 4);
    float* shift1  = (float*)alloc(64 * 4);
    float* scale2  = (float*)alloc(64 * 4);
    float* shift2  = (float*)alloc(64 * 4);
    float* pooled  = (float*)alloc(N_GRAPHS * 64 * 4);
    float* pcnt    = (float*)alloc(N_GRAPHS * 4);
    uint2* ebuf2   = (uint2*)alloc((size_t)N_EDGES * 8);
    float* bufA    = (float*)alloc((size_t)N_NODES * 64 * 4);
    float* bufB    = (float*)alloc((size_t)N_NODES * 64 * 4);
    // ebuf (unsorted, bucket-grouped) is dead before GEMM1 writes bufA: alias them.
    uint2* ebuf    = (uint2*)bufA;
    if (o > ws_size) return;

    (void)hipMemsetAsync(cnt2, 0, NCNT * 4, stream);
    (void)hipMemsetAsync(deg, 0, N_NODES * 4, stream);
    (void)hipMemsetAsync(bnshard, 0, NSHARD * 128 * 4, stream);
    (void)hipMemsetAsync(pooled, 0, N_GRAPHS * 64 * 4, stream);
    (void)hipMemsetAsync(pcnt, 0, N_GRAPHS * 4, stream);

    k_count<<<BIN_GRID, 256, 0, stream>>>(ei, cnt2);
    k_scan6k<<<1, 256, 0, stream>>>(cnt2, soff, cur, nptr);
    k_bin<<<BIN_GRID, 256, 0, stream>>>(ei, ew, cur, ebuf, deg);
    k_dinv<<<(N_NODES + 255) / 256, 256, 0, stream>>>(deg, dinv);
    k_sortnorm<<<NBUCK, 256, 0, stream>>>(ebuf, soff, dinv, ebuf2, nptr);

    // layer 1
    k_gemm<128, false><<<(N_NODES + 127) / 128, 256, 0, stream>>>(x, W1, nullptr, nullptr, bufA);
    k_agg<<<(N_NODES + 31) / 32, 256, 0, stream>>>(bufA, ebuf2, nptr, dinv, b1, bufB, bnshard);
    k_bn_final<<<1, 256, 0, stream>>>(bnshard, g1, be1, scale1, shift1);

    // layer 2
    k_gemm<64, true><<<(N_NODES + 127) / 128, 256, 0, stream>>>(bufB, W2, scale1, shift1, bufA);
    k_agg<<<(N_NODES + 31) / 32, 256, 0, stream>>>(bufA, ebuf2, nptr, dinv, b2, bufB, bnshard);
    k_bn_final<<<1, 256, 0, stream>>>(bnshard, g2, be2, scale2, shift2);

    // pool + output
    k_pool<<<(N_NODES + 1023) / 1024, 256, 0, stream>>>(bufB, scale2, shift2, batch, pooled, pcnt);
    k_out<<<1, 64, 0, stream>>>(pooled, pcnt, Wout, bout, out);
}

// Round 7
// 914.859 us; speedup vs baseline: 1.1530x; 1.1530x over previous
//
#include <hip/hip_runtime.h>
#include <stdint.h>

#define N_NODES 100000
#define N_EDGES 3200000
#define IN_DIM 128
#define HID 64
#define N_GRAPHS 64
#define BN_EPS 1e-5f
#define NSHARD 16
#define BUCK_SH 7
#define BUCK_SZ 128
#define NBUCK ((N_NODES + BUCK_SZ - 1) / BUCK_SZ)   // 782
#define NCNT (NBUCK * 8)                             // 6256
#define NCHUNK (N_EDGES / 4)                         // 800000
#define BIN_GRID (NCHUNK / 256)                      // 3125 blocks, 1 chunk/thread
#define EDGE_CAP 6016                                // LDS edge stage (mean 4092)

// __builtin_nontemporal_load needs native (ext_vector) types, not HIP structs.
typedef float vf4 __attribute__((ext_vector_type(4)));
typedef int   vi4 __attribute__((ext_vector_type(4)));
typedef unsigned vu2 __attribute__((ext_vector_type(2)));

__device__ __forceinline__ float4 nt_f4(const float* p) {
    vf4 v = __builtin_nontemporal_load((const vf4*)p);
    return make_float4(v.x, v.y, v.z, v.w);
}
__device__ __forceinline__ int4 nt_i4(const int* p) {
    vi4 v = __builtin_nontemporal_load((const vi4*)p);
    return make_int4(v.x, v.y, v.z, v.w);
}
__device__ __forceinline__ uint2 nt_u2(const uint2* p) {
    vu2 v = __builtin_nontemporal_load((const vu2*)p);
    return make_uint2(v.x, v.y);
}
__device__ __forceinline__ float nt_f(const float* p) {
    return __builtin_nontemporal_load(p);
}

// ---------------------------------------------------------------------------
// count edges per (bucket, sub-stream). chunk ch covers edges 4ch..4ch+3;
// s=(ch>>8)&7 == blockIdx&7 == XCD id -> cursor regions are XCD-local.
__global__ void k_count(const int* __restrict__ ei, int* __restrict__ cnt2) {
    int stride = gridDim.x * blockDim.x;
    for (int ch = blockIdx.x * blockDim.x + threadIdx.x; ch < NCHUNK; ch += stride) {
        int4 c4 = nt_i4(ei + N_EDGES + 4 * ch);
        int s = (ch >> 8) & 7;
        atomicAdd(&cnt2[((c4.x >> BUCK_SH) << 3) + s], 1);
        atomicAdd(&cnt2[((c4.y >> BUCK_SH) << 3) + s], 1);
        atomicAdd(&cnt2[((c4.z >> BUCK_SH) << 3) + s], 1);
        atomicAdd(&cnt2[((c4.w >> BUCK_SH) << 3) + s], 1);
    }
}

// single-block exclusive scan of cnt2[6256] -> soff[6257]; init cursors; nptr tail
__global__ void k_scan6k(const int* __restrict__ cnt2, int* __restrict__ soff,
                         int* __restrict__ cur, int* __restrict__ nptr) {
    __shared__ int parts[256];
    int t = threadIdx.x;
    int s = 0;
    for (int i = 0; i < 25; ++i) {
        int idx = t * 25 + i;
        if (idx < NCNT) s += cnt2[idx];
    }
    parts[t] = s;
    __syncthreads();
    for (int off = 1; off < 256; off <<= 1) {
        int x = (t >= off) ? parts[t - off] : 0;
        __syncthreads();
        parts[t] += x;
        __syncthreads();
    }
    int run = (t > 0) ? parts[t - 1] : 0;
    for (int i = 0; i < 25; ++i) {
        int idx = t * 25 + i;
        if (idx < NCNT) {
            soff[idx] = run;
            cur[idx] = run;
            run += cnt2[idx];
        }
    }
    if (t == 255) soff[NCNT] = parts[255];
    if (t == 0) nptr[N_NODES] = N_EDGES;
}

// bin edges into bucket-substream regions: ebuf[p] = {r | (c_local<<17), w}
// (degree fusion removed: the random global f32 atomics caused cross-XCD
//  line ping-pong, +94 MB writes, +162 us — round-6 post-mortem)
__global__ void k_bin(const int* __restrict__ ei, const float* __restrict__ ew,
                      int* __restrict__ cur, uint2* __restrict__ ebuf) {
    int stride = gridDim.x * blockDim.x;
    for (int ch = blockIdx.x * blockDim.x + threadIdx.x; ch < NCHUNK; ch += stride) {
        int4 r4 = nt_i4(ei + 4 * ch);
        int4 c4 = nt_i4(ei + N_EDGES + 4 * ch);
        float4 w4 = nt_f4(ew + 4 * ch);
        int s = (ch >> 8) & 7;
        int rr[4] = {r4.x, r4.y, r4.z, r4.w};
        int cc[4] = {c4.x, c4.y, c4.z, c4.w};
        float ww[4] = {w4.x, w4.y, w4.z, w4.w};
#pragma unroll
        for (int u = 0; u < 4; ++u) {
            int p = atomicAdd(&cur[((cc[u] >> BUCK_SH) << 3) + s], 1);
            ebuf[p] = make_uint2((unsigned)(rr[u] | ((cc[u] & (BUCK_SZ - 1)) << 17)),
                                 __float_as_uint(ww[u]));
        }
    }
}

// per-bucket weighted degree -> dinv. All edges of col c are bucket-local,
// so only LDS atomics + one streaming read. Completes before k_sortnorm
// launches -> k_sortnorm may read any dinv[r] (no cross-block race).
__global__ __launch_bounds__(256) void k_degb(const uint2* __restrict__ ebuf,
                                              const int* __restrict__ soff,
                                              float* __restrict__ dinv) {
    __shared__ float dacc[BUCK_SZ];
    int b = blockIdx.x, t = threadIdx.x;
    if (t < BUCK_SZ) dacc[t] = 0.f;
    __syncthreads();
    int beg = soff[b << 3], end = soff[(b << 3) + 8];
    for (int i = beg + t; i < end; i += 256) {
        uint2 u = nt_u2(ebuf + i);
        atomicAdd(&dacc[u.x >> 17], __uint_as_float(u.y));
    }
    __syncthreads();
    int node = b * BUCK_SZ + t;
    if (t < BUCK_SZ && node < N_NODES) dinv[node] = rsqrtf(dacc[t] + 1.0f);
}

// ---------------------------------------------------------------------------
// per-bucket counting sort by local dest + norm. Stages edges in LDS (one
// global read pass). dinv fully computed before this launches (no race).
__global__ __launch_bounds__(256) void k_sortnorm(const uint2* __restrict__ ebuf,
                                                  const int* __restrict__ soff,
                                                  const float* __restrict__ dinv,
                                                  uint2* __restrict__ ebuf2,
                                                  int* __restrict__ nptr) {
    __shared__ uint2 se[EDGE_CAP];
    __shared__ float sdi[BUCK_SZ];
    __shared__ int scnt[BUCK_SZ];
    __shared__ int scur[BUCK_SZ];
    int b = blockIdx.x, t = threadIdx.x;
    if (t < BUCK_SZ) {
        scnt[t] = 0;
        int node = b * BUCK_SZ + t;
        sdi[t] = (node < N_NODES) ? dinv[node] : 0.f;
    }
    __syncthreads();
    int beg = soff[b << 3], end = soff[(b << 3) + 8];
    int n = end - beg;
    bool fit = (n <= EDGE_CAP);
    // pass 1: stage edges + dest histogram
    for (int i = t; i < n; i += 256) {
        uint2 u = nt_u2(ebuf + beg + i);
        if (fit) se[i] = u;
        atomicAdd(&scnt[u.x >> 17], 1);
    }
    __syncthreads();
    // inclusive scan over 128 counts (all 256 threads hit barriers)
    for (int off = 1; off < BUCK_SZ; off <<= 1) {
        int x = 0;
        if (t < BUCK_SZ && t >= off) x = scnt[t - off];
        __syncthreads();
        if (t < BUCK_SZ) scnt[t] += x;
        __syncthreads();
    }
    if (t < BUCK_SZ) {
        int excl = (t > 0) ? scnt[t - 1] : 0;
        scur[t] = beg + excl;
        int node = b * BUCK_SZ + t;
        if (node < N_NODES) nptr[node] = beg + excl;
    }
    __syncthreads();
    // pass 2: scatter within bucket (L2/L3-resident window) + norm
    for (int i = t; i < n; i += 256) {
        uint2 u = fit ? se[i] : nt_u2(ebuf + beg + i);
        int r = u.x & 131071;
        int cl = u.x >> 17;
        float nm = dinv[r] * __uint_as_float(u.y) * sdi[cl];
        int p = atomicAdd(&scur[cl], 1);
        ebuf2[p] = make_uint2((unsigned)r, __float_as_uint(nm));
    }
}

// ---------------------------------------------------------------------------
// GEMM: out[n][c] = sum_k in[n][k] * W[k][c], optional fused BN+ReLU on input
template <int K, bool BN>
__global__ __launch_bounds__(256) void k_gemm(const float* __restrict__ in,
                                              const float* __restrict__ W,
                                              const float* __restrict__ scale,
                                              const float* __restrict__ shift,
                                              float* __restrict__ out) {
    __shared__ float ws[K * 64];
    __shared__ float xs[32 * 132];
    __shared__ float ssc[64], ssh[64];
    int t = threadIdx.x;
    int nbase = blockIdx.x * 128;

#pragma unroll
    for (int i = 0; i < K / 16; ++i) {
        int idx = t + 256 * i;
        ((float4*)ws)[idx] = ((const float4*)W)[idx];
    }
    if (BN && t < 64) { ssc[t] = scale[t]; ssh[t] = shift[t]; }

    int cg = t & 15;
    int ng = t >> 4;
    float acc[8][4];
#pragma unroll
    for (int i = 0; i < 8; ++i)
#pragma unroll
        for (int j = 0; j < 4; ++j) acc[i][j] = 0.f;

    for (int k0 = 0; k0 < K; k0 += 32) {
        __syncthreads();
#pragma unroll
        for (int i = 0; i < 4; ++i) {
            int idx = t + 256 * i;
            int row = idx >> 3;
            int kq = idx & 7;
            int node = nbase + row;
            float4 v = make_float4(0.f, 0.f, 0.f, 0.f);
            if (node < N_NODES)
                v = nt_f4(in + (size_t)node * K + k0 + kq * 4);
            float vv[4] = {v.x, v.y, v.z, v.w};
#pragma unroll
            for (int u = 0; u < 4; ++u) {
                float val = vv[u];
                if (BN) {
                    int k = k0 + kq * 4 + u;
                    val = fmaxf(ssc[k] * val + ssh[k], 0.f);
                }
                xs[(kq * 4 + u) * 132 + row] = val;
            }
        }
        __syncthreads();
#pragma unroll
        for (int k = 0; k < 32; ++k) {
            float4 wv = *(const float4*)(ws + (k0 + k) * 64 + cg * 4);
            float4 xa = *(const float4*)(xs + k * 132 + ng * 8);
            float4 xb = *(const float4*)(xs + k * 132 + ng * 8 + 4);
            float xv[8] = {xa.x, xa.y, xa.z, xa.w, xb.x, xb.y, xb.z, xb.w};
            float wvv[4] = {wv.x, wv.y, wv.z, wv.w};
#pragma unroll
            for (int i = 0; i < 8; ++i)
#pragma unroll
                for (int j = 0; j < 4; ++j) acc[i][j] += xv[i] * wvv[j];
        }
    }
#pragma unroll
    for (int i = 0; i < 8; ++i) {
        int node = nbase + ng * 8 + i;
        if (node < N_NODES) {
            float4 o4 = make_float4(acc[i][0], acc[i][1], acc[i][2], acc[i][3]);
            *(float4*)(out + (size_t)node * 64 + cg * 4) = o4;
        }
    }
}

// ---------------------------------------------------------------------------
// CSR gather-aggregation: wave per node (lane=channel), register accumulation,
// explicit 8-deep load pipelining for MLP. Fused self-loop, bias, BN partials.
__global__ __launch_bounds__(256) void k_agg(const float* __restrict__ hin,
                                             const uint2* __restrict__ ebuf2,
                                             const int* __restrict__ nptr,
                                             const float* __restrict__ dinv,
                                             const float* __restrict__ bias,
                                             float* __restrict__ hout,
                                             float* __restrict__ bn_shard) {
    int wave = threadIdx.x >> 6;
    int lane = threadIdx.x & 63;
    float s = 0.f, q = 0.f;
    float bl = bias[lane];
    int vbase = blockIdx.x * 32 + wave * 8;
    for (int vi = 0; vi < 8; ++vi) {
        int v = vbase + vi;
        if (v >= N_NODES) break;
        int beg = nptr[v], end = nptr[v + 1];
        float acc = 0.f;
        int j = beg;
        for (; j + 8 <= end; j += 8) {
            float fv[8], fn[8];
#pragma unroll
            for (int u = 0; u < 8; ++u) {
                uint2 e = nt_u2(ebuf2 + j + u);
                fn[u] = __uint_as_float(e.y);
                fv[u] = hin[((size_t)e.x << 6) + lane];
            }
#pragma unroll
            for (int u = 0; u < 8; ++u) acc = fmaf(fn[u], fv[u], acc);
        }
        for (; j < end; ++j) {
            uint2 e = nt_u2(ebuf2 + j);
            acc = fmaf(__uint_as_float(e.y), hin[((size_t)e.x << 6) + lane], acc);
        }
        float dv = dinv[v];
        acc = fmaf(dv * dv, hin[((size_t)v << 6) + lane], acc);
        acc += bl;
        hout[((size_t)v << 6) + lane] = acc;
        s += acc;
        q += acc * acc;
    }
    __shared__ float sm[4][64], qm[4][64];
    sm[wave][lane] = s;
    qm[wave][lane] = q;
    __syncthreads();
    if (wave == 0) {
        float ts = sm[0][lane] + sm[1][lane] + sm[2][lane] + sm[3][lane];
        float tq = qm[0][lane] + qm[1][lane] + qm[2][lane] + qm[3][lane];
        float* shard = bn_shard + (blockIdx.x & (NSHARD - 1)) * 128;
        atomicAdd(&shard[lane], ts);
        atomicAdd(&shard[64 + lane], tq);
    }
}

// reduce BN shards -> scale/shift; re-zero shards for the next layer
__global__ void k_bn_final(float* __restrict__ bn_shard, const float* __restrict__ gamma,
                           const float* __restrict__ beta, float* __restrict__ scale,
                           float* __restrict__ shift) {
    int t = threadIdx.x;
    if (t < 64) {
        float s = 0.f, q = 0.f;
        for (int i = 0; i < NSHARD; ++i) {
            s += bn_shard[i * 128 + t];
            q += bn_shard[i * 128 + 64 + t];
        }
        float mean = s * (1.0f / N_NODES);
        float var = q * (1.0f / N_NODES) - mean * mean;
        float sc = gamma[t] * rsqrtf(var + BN_EPS);
        scale[t] = sc;
        shift[t] = beta[t] - mean * sc;
    }
    __syncthreads();
    for (int i = t; i < NSHARD * 128; i += 256) bn_shard[i] = 0.f;
}

// ---------------------------------------------------------------------------
__global__ __launch_bounds__(256) void k_pool(const float* __restrict__ a2,
                                              const float* __restrict__ scale,
                                              const float* __restrict__ shift,
                                              const int* __restrict__ batch,
                                              float* __restrict__ pooled,
                                              float* __restrict__ pcnt) {
    int t = threadIdx.x;
    int c = t & 63;
    int rg = t >> 6;
    int base = blockIdx.x * 1024;
    float sc = scale[c], sh = shift[c];
    int gcur = -1;
    float acc = 0.f, cacc = 0.f;
    for (int i = rg; i < 1024; i += 4) {
        int v = base + i;
        if (v >= N_NODES) break;
        int g = batch[v];
        if (g != gcur) {
            if (gcur >= 0) {
                atomicAdd(&pooled[gcur * 64 + c], acc);
                if (c == 0) atomicAdd(&pcnt[gcur], cacc);
            }
            gcur = g;
            acc = 0.f;
            cacc = 0.f;
        }
        float h = fmaxf(sc * nt_f(a2 + (size_t)v * 64 + c) + sh, 0.f);
        acc += h;
        cacc += 1.f;
    }
    if (gcur >= 0) {
        atomicAdd(&pooled[gcur * 64 + c], acc);
        if (c == 0) atomicAdd(&pcnt[gcur], cacc);
    }
}

__global__ void k_out(const float* __restrict__ pooled, const float* __restrict__ pcnt,
                      const float* __restrict__ Wout, const float* __restrict__ bout,
                      float* __restrict__ out) {
    int g = threadIdx.x;
    if (g < N_GRAPHS) {
        float cnt = fmaxf(pcnt[g], 1.0f);
        float s = 0.f;
        for (int c = 0; c < 64; ++c) s += pooled[g * 64 + c] * Wout[c];
        out[g] = s / cnt + bout[0];
    }
}

// ---------------------------------------------------------------------------
extern "C" void kernel_launch(void* const* d_in, const int* in_sizes, int n_in,
                              void* d_out, int out_size, void* d_ws, size_t ws_size,
                              hipStream_t stream) {
    const float* x    = (const float*)d_in[0];
    const int*   ei   = (const int*)d_in[1];
    const float* ew   = (const float*)d_in[2];
    const int*   batch= (const int*)d_in[3];
    const float* W1   = (const float*)d_in[4];
    const float* b1   = (const float*)d_in[5];
    const float* W2   = (const float*)d_in[6];
    const float* b2   = (const float*)d_in[7];
    const float* g1   = (const float*)d_in[8];
    const float* be1  = (const float*)d_in[9];
    const float* g2   = (const float*)d_in[10];
    const float* be2  = (const float*)d_in[11];
    const float* Wout = (const float*)d_in[12];
    const float* bout = (const float*)d_in[13];
    float* out = (float*)d_out;

    char* w = (char*)d_ws;
    size_t o = 0;
    auto alloc = [&](size_t bytes) -> void* {
        void* p = w + o;
        o = (o + bytes + 255) & ~(size_t)255;
        return p;
    };
    int*   cnt2    = (int*)alloc(NCNT * 4);
    int*   soff    = (int*)alloc((NCNT + 1) * 4);
    int*   cur     = (int*)alloc(NCNT * 4);
    int*   nptr    = (int*)alloc((N_NODES + 1) * 4);
    float* dinv    = (float*)alloc(N_NODES * 4);
    float* bnshard = (float*)alloc(NSHARD * 128 * 4);
    float* scale1  = (float*)alloc(64 * 4);
    float* shift1  = (float*)alloc(64 * 4);
    float* scale2  = (float*)alloc(64 * 4);
    float* shift2  = (float*)alloc(64 * 4);
    float* pooled  = (float*)alloc(N_GRAPHS * 64 * 4);
    float* pcnt    = (float*)alloc(N_GRAPHS * 4);
    uint2* ebuf2   = (uint2*)alloc((size_t)N_EDGES * 8);
    float* bufA    = (float*)alloc((size_t)N_NODES * 64 * 4);
    float* bufB    = (float*)alloc((size_t)N_NODES * 64 * 4);
    // ebuf (unsorted, bucket-grouped) is dead before GEMM1 writes bufA: alias them.
    uint2* ebuf    = (uint2*)bufA;
    if (o > ws_size) return;

    (void)hipMemsetAsync(cnt2, 0, NCNT * 4, stream);
    (void)hipMemsetAsync(bnshard, 0, NSHARD * 128 * 4, stream);
    (void)hipMemsetAsync(pooled, 0, N_GRAPHS * 64 * 4, stream);
    (void)hipMemsetAsync(pcnt, 0, N_GRAPHS * 4, stream);

    k_count<<<BIN_GRID, 256, 0, stream>>>(ei, cnt2);
    k_scan6k<<<1, 256, 0, stream>>>(cnt2, soff, cur, nptr);
    k_bin<<<BIN_GRID, 256, 0, stream>>>(ei, ew, cur, ebuf);
    k_degb<<<NBUCK, 256, 0, stream>>>(ebuf, soff, dinv);
    k_sortnorm<<<NBUCK, 256, 0, stream>>>(ebuf, soff, dinv, ebuf2, nptr);

    // layer 1
    k_gemm<128, false><<<(N_NODES + 127) / 128, 256, 0, stream>>>(x, W1, nullptr, nullptr, bufA);
    k_agg<<<(N_NODES + 31) / 32, 256, 0, stream>>>(bufA, ebuf2, nptr, dinv, b1, bufB, bnshard);
    k_bn_final<<<1, 256, 0, stream>>>(bnshard, g1, be1, scale1, shift1);

    // layer 2
    k_gemm<64, true><<<(N_NODES + 127) / 128, 256, 0, stream>>>(bufB, W2, scale1, shift1, bufA);
    k_agg<<<(N_NODES + 31) / 32, 256, 0, stream>>>(bufA, ebuf2, nptr, dinv, b2, bufB, bnshard);
    k_bn_final<<<1, 256, 0, stream>>>(bnshard, g2, be2, scale2, shift2);

    // pool + output
    k_pool<<<(N_NODES + 1023) / 1024, 256, 0, stream>>>(bufB, scale2, shift2, batch, pooled, pcnt);
    k_out<<<1, 64, 0, stream>>>(pooled, pcnt, Wout, bout, out);
}

// Round 8
// 695.121 us; speedup vs baseline: 1.5175x; 1.3161x over previous
//
#include <hip/hip_runtime.h>
#include <stdint.h>

#define N_NODES 100000
#define N_EDGES 3200000
#define IN_DIM 128
#define HID 64
#define N_GRAPHS 64
#define BN_EPS 1e-5f
#define NSHARD 16
#define BUCK_SH 7
#define BUCK_SZ 128
#define NBUCK ((N_NODES + BUCK_SZ - 1) / BUCK_SZ)   // 782
#define NCNT (NBUCK * 8)                             // 6256
#define BINB_EDGES 4096                              // edges per binning block
#define BIN_BLOCKS ((N_EDGES + BINB_EDGES - 1) / BINB_EDGES)  // 782
#define EDGE_CAP 6016                                // LDS edge stage (mean 4092)

// __builtin_nontemporal_load needs native (ext_vector) types, not HIP structs.
typedef float vf4 __attribute__((ext_vector_type(4)));
typedef int   vi4 __attribute__((ext_vector_type(4)));
typedef unsigned vu2 __attribute__((ext_vector_type(2)));

__device__ __forceinline__ float4 nt_f4(const float* p) {
    vf4 v = __builtin_nontemporal_load((const vf4*)p);
    return make_float4(v.x, v.y, v.z, v.w);
}
__device__ __forceinline__ int4 nt_i4(const int* p) {
    vi4 v = __builtin_nontemporal_load((const vi4*)p);
    return make_int4(v.x, v.y, v.z, v.w);
}
__device__ __forceinline__ uint2 nt_u2(const uint2* p) {
    vu2 v = __builtin_nontemporal_load((const vu2*)p);
    return make_uint2(v.x, v.y);
}
__device__ __forceinline__ float nt_f(const float* p) {
    return __builtin_nontemporal_load(p);
}

// ---------------------------------------------------------------------------
// block-aggregated count: LDS histogram per block (4096 edges), then ONE
// global atomic per non-empty (bucket, s). s = blockIdx&7 = XCD id; k_bin
// uses the identical block->edge partition so counts match reservations.
__global__ __launch_bounds__(256) void k_count(const int* __restrict__ ei,
                                               int* __restrict__ cnt2) {
    __shared__ int hist[NBUCK];
    int b = blockIdx.x, t = threadIdx.x;
    int s = b & 7;
    int base = b * BINB_EDGES;
    int n = min(BINB_EDGES, N_EDGES - base);
    for (int i = t; i < NBUCK; i += 256) hist[i] = 0;
    __syncthreads();
#pragma unroll
    for (int k = 0; k < 4; ++k) {
        int ch = t + 256 * k;
        if (4 * ch < n) {
            int4 c4 = nt_i4(ei + N_EDGES + base + 4 * ch);
            atomicAdd(&hist[c4.x >> BUCK_SH], 1);
            atomicAdd(&hist[c4.y >> BUCK_SH], 1);
            atomicAdd(&hist[c4.z >> BUCK_SH], 1);
            atomicAdd(&hist[c4.w >> BUCK_SH], 1);
        }
    }
    __syncthreads();
    for (int j = t; j < NBUCK; j += 256) {
        int h = hist[j];
        if (h > 0) atomicAdd(&cnt2[(j << 3) + s], h);
    }
}

// single-block exclusive scan of cnt2[6256] -> soff[6257]; init cursors; nptr tail
__global__ void k_scan6k(const int* __restrict__ cnt2, int* __restrict__ soff,
                         int* __restrict__ cur, int* __restrict__ nptr) {
    __shared__ int parts[256];
    int t = threadIdx.x;
    int s = 0;
    for (int i = 0; i < 25; ++i) {
        int idx = t * 25 + i;
        if (idx < NCNT) s += cnt2[idx];
    }
    parts[t] = s;
    __syncthreads();
    for (int off = 1; off < 256; off <<= 1) {
        int x = (t >= off) ? parts[t - off] : 0;
        __syncthreads();
        parts[t] += x;
        __syncthreads();
    }
    int run = (t > 0) ? parts[t - 1] : 0;
    for (int i = 0; i < 25; ++i) {
        int idx = t * 25 + i;
        if (idx < NCNT) {
            soff[idx] = run;
            cur[idx] = run;
            run += cnt2[idx];
        }
    }
    if (t == 255) soff[NCNT] = parts[255];
    if (t == 0) nptr[N_NODES] = N_EDGES;
}

// block-aggregated bin: stage 4096 edges in LDS, histogram, reserve one global
// range per non-empty bucket (atomicAdd on XCD-local cursor), scatter from LDS.
// Global atomics: ~600/block (was 4096/block) — removes the ~96 MB of
// cursor-atomic write traffic identified in round-6/7 post-mortems.
__global__ __launch_bounds__(256) void k_bin(const int* __restrict__ ei,
                                             const float* __restrict__ ew,
                                             int* __restrict__ cur,
                                             uint2* __restrict__ ebuf) {
    __shared__ uint2 sed[BINB_EDGES];           // packed edge {r|cl<<17, w}
    __shared__ unsigned short sbk[BINB_EDGES];  // bucket id per edge
    __shared__ int hist[NBUCK];                 // count -> global cursor
    int b = blockIdx.x, t = threadIdx.x;
    int s = b & 7;
    int base = b * BINB_EDGES;
    int n = min(BINB_EDGES, N_EDGES - base);
    for (int i = t; i < NBUCK; i += 256) hist[i] = 0;
    __syncthreads();
    // pass A: stage + LDS histogram
#pragma unroll
    for (int k = 0; k < 4; ++k) {
        int ch = t + 256 * k;
        if (4 * ch < n) {
            int4 r4 = nt_i4(ei + base + 4 * ch);
            int4 c4 = nt_i4(ei + N_EDGES + base + 4 * ch);
            float4 w4 = nt_f4(ew + base + 4 * ch);
            int rr[4] = {r4.x, r4.y, r4.z, r4.w};
            int cc[4] = {c4.x, c4.y, c4.z, c4.w};
            float ww[4] = {w4.x, w4.y, w4.z, w4.w};
#pragma unroll
            for (int u = 0; u < 4; ++u) {
                int li = 4 * ch + u;
                sed[li] = make_uint2(
                    (unsigned)(rr[u] | ((cc[u] & (BUCK_SZ - 1)) << 17)),
                    __float_as_uint(ww[u]));
                int bk = cc[u] >> BUCK_SH;
                sbk[li] = (unsigned short)bk;
                atomicAdd(&hist[bk], 1);
            }
        }
    }
    __syncthreads();
    // pass B: reserve global ranges; hist[j] becomes the running global cursor
    for (int j = t; j < NBUCK; j += 256) {
        int h = hist[j];
        if (h > 0) hist[j] = atomicAdd(&cur[(j << 3) + s], h);
    }
    __syncthreads();
    // pass C: scatter from LDS to reserved ranges (LDS-atomic local cursors)
    for (int i = t; i < n; i += 256) {
        int bk = sbk[i];
        int pos = atomicAdd(&hist[bk], 1);
        ebuf[pos] = sed[i];
    }
}

// per-bucket weighted degree -> dinv. All edges of col c are bucket-local,
// so only LDS atomics + one streaming read. Completes before k_sortnorm
// launches -> k_sortnorm may read any dinv[r] (no cross-block race).
__global__ __launch_bounds__(256) void k_degb(const uint2* __restrict__ ebuf,
                                              const int* __restrict__ soff,
                                              float* __restrict__ dinv) {
    __shared__ float dacc[BUCK_SZ];
    int b = blockIdx.x, t = threadIdx.x;
    if (t < BUCK_SZ) dacc[t] = 0.f;
    __syncthreads();
    int beg = soff[b << 3], end = soff[(b << 3) + 8];
    for (int i = beg + t; i < end; i += 256) {
        uint2 u = nt_u2(ebuf + i);
        atomicAdd(&dacc[u.x >> 17], __uint_as_float(u.y));
    }
    __syncthreads();
    int node = b * BUCK_SZ + t;
    if (t < BUCK_SZ && node < N_NODES) dinv[node] = rsqrtf(dacc[t] + 1.0f);
}

// ---------------------------------------------------------------------------
// per-bucket counting sort by local dest + norm. Stages edges in LDS (one
// global read pass). dinv fully computed before this launches (no race).
__global__ __launch_bounds__(256) void k_sortnorm(const uint2* __restrict__ ebuf,
                                                  const int* __restrict__ soff,
                                                  const float* __restrict__ dinv,
                                                  uint2* __restrict__ ebuf2,
                                                  int* __restrict__ nptr) {
    __shared__ uint2 se[EDGE_CAP];
    __shared__ float sdi[BUCK_SZ];
    __shared__ int scnt[BUCK_SZ];
    __shared__ int scur[BUCK_SZ];
    int b = blockIdx.x, t = threadIdx.x;
    if (t < BUCK_SZ) {
        scnt[t] = 0;
        int node = b * BUCK_SZ + t;
        sdi[t] = (node < N_NODES) ? dinv[node] : 0.f;
    }
    __syncthreads();
    int beg = soff[b << 3], end = soff[(b << 3) + 8];
    int n = end - beg;
    bool fit = (n <= EDGE_CAP);
    // pass 1: stage edges + dest histogram
    for (int i = t; i < n; i += 256) {
        uint2 u = nt_u2(ebuf + beg + i);
        if (fit) se[i] = u;
        atomicAdd(&scnt[u.x >> 17], 1);
    }
    __syncthreads();
    // inclusive scan over 128 counts (all 256 threads hit barriers)
    for (int off = 1; off < BUCK_SZ; off <<= 1) {
        int x = 0;
        if (t < BUCK_SZ && t >= off) x = scnt[t - off];
        __syncthreads();
        if (t < BUCK_SZ) scnt[t] += x;
        __syncthreads();
    }
    if (t < BUCK_SZ) {
        int excl = (t > 0) ? scnt[t - 1] : 0;
        scur[t] = beg + excl;
        int node = b * BUCK_SZ + t;
        if (node < N_NODES) nptr[node] = beg + excl;
    }
    __syncthreads();
    // pass 2: scatter within bucket (L2/L3-resident window) + norm
    for (int i = t; i < n; i += 256) {
        uint2 u = fit ? se[i] : nt_u2(ebuf + beg + i);
        int r = u.x & 131071;
        int cl = u.x >> 17;
        float nm = dinv[r] * __uint_as_float(u.y) * sdi[cl];
        int p = atomicAdd(&scur[cl], 1);
        ebuf2[p] = make_uint2((unsigned)r, __float_as_uint(nm));
    }
}

// ---------------------------------------------------------------------------
// GEMM: out[n][c] = sum_k in[n][k] * W[k][c], optional fused BN+ReLU on input
template <int K, bool BN>
__global__ __launch_bounds__(256) void k_gemm(const float* __restrict__ in,
                                              const float* __restrict__ W,
                                              const float* __restrict__ scale,
                                              const float* __restrict__ shift,
                                              float* __restrict__ out) {
    __shared__ float ws[K * 64];
    __shared__ float xs[32 * 132];
    __shared__ float ssc[64], ssh[64];
    int t = threadIdx.x;
    int nbase = blockIdx.x * 128;

#pragma unroll
    for (int i = 0; i < K / 16; ++i) {
        int idx = t + 256 * i;
        ((float4*)ws)[idx] = ((const float4*)W)[idx];
    }
    if (BN && t < 64) { ssc[t] = scale[t]; ssh[t] = shift[t]; }

    int cg = t & 15;
    int ng = t >> 4;
    float acc[8][4];
#pragma unroll
    for (int i = 0; i < 8; ++i)
#pragma unroll
        for (int j = 0; j < 4; ++j) acc[i][j] = 0.f;

    for (int k0 = 0; k0 < K; k0 += 32) {
        __syncthreads();
#pragma unroll
        for (int i = 0; i < 4; ++i) {
            int idx = t + 256 * i;
            int row = idx >> 3;
            int kq = idx & 7;
            int node = nbase + row;
            float4 v = make_float4(0.f, 0.f, 0.f, 0.f);
            if (node < N_NODES)
                v = nt_f4(in + (size_t)node * K + k0 + kq * 4);
            float vv[4] = {v.x, v.y, v.z, v.w};
#pragma unroll
            for (int u = 0; u < 4; ++u) {
                float val = vv[u];
                if (BN) {
                    int k = k0 + kq * 4 + u;
                    val = fmaxf(ssc[k] * val + ssh[k], 0.f);
                }
                xs[(kq * 4 + u) * 132 + row] = val;
            }
        }
        __syncthreads();
#pragma unroll
        for (int k = 0; k < 32; ++k) {
            float4 wv = *(const float4*)(ws + (k0 + k) * 64 + cg * 4);
            float4 xa = *(const float4*)(xs + k * 132 + ng * 8);
            float4 xb = *(const float4*)(xs + k * 132 + ng * 8 + 4);
            float xv[8] = {xa.x, xa.y, xa.z, xa.w, xb.x, xb.y, xb.z, xb.w};
            float wvv[4] = {wv.x, wv.y, wv.z, wv.w};
#pragma unroll
            for (int i = 0; i < 8; ++i)
#pragma unroll
                for (int j = 0; j < 4; ++j) acc[i][j] += xv[i] * wvv[j];
        }
    }
#pragma unroll
    for (int i = 0; i < 8; ++i) {
        int node = nbase + ng * 8 + i;
        if (node < N_NODES) {
            float4 o4 = make_float4(acc[i][0], acc[i][1], acc[i][2], acc[i][3]);
            *(float4*)(out + (size_t)node * 64 + cg * 4) = o4;
        }
    }
}

// ---------------------------------------------------------------------------
// CSR gather-aggregation: wave per node (lane=channel), register accumulation,
// explicit 8-deep load pipelining for MLP. Fused self-loop, bias, BN partials.
__global__ __launch_bounds__(256) void k_agg(const float* __restrict__ hin,
                                             const uint2* __restrict__ ebuf2,
                                             const int* __restrict__ nptr,
                                             const float* __restrict__ dinv,
                                             const float* __restrict__ bias,
                                             float* __restrict__ hout,
                                             float* __restrict__ bn_shard) {
    int wave = threadIdx.x >> 6;
    int lane = threadIdx.x & 63;
    float s = 0.f, q = 0.f;
    float bl = bias[lane];
    int vbase = blockIdx.x * 32 + wave * 8;
    for (int vi = 0; vi < 8; ++vi) {
        int v = vbase + vi;
        if (v >= N_NODES) break;
        int beg = nptr[v], end = nptr[v + 1];
        float acc = 0.f;
        int j = beg;
        for (; j + 8 <= end; j += 8) {
            float fv[8], fn[8];
#pragma unroll
            for (int u = 0; u < 8; ++u) {
                uint2 e = nt_u2(ebuf2 + j + u);
                fn[u] = __uint_as_float(e.y);
                fv[u] = hin[((size_t)e.x << 6) + lane];
            }
#pragma unroll
            for (int u = 0; u < 8; ++u) acc = fmaf(fn[u], fv[u], acc);
        }
        for (; j < end; ++j) {
            uint2 e = nt_u2(ebuf2 + j);
            acc = fmaf(__uint_as_float(e.y), hin[((size_t)e.x << 6) + lane], acc);
        }
        float dv = dinv[v];
        acc = fmaf(dv * dv, hin[((size_t)v << 6) + lane], acc);
        acc += bl;
        hout[((size_t)v << 6) + lane] = acc;
        s += acc;
        q += acc * acc;
    }
    __shared__ float sm[4][64], qm[4][64];
    sm[wave][lane] = s;
    qm[wave][lane] = q;
    __syncthreads();
    if (wave == 0) {
        float ts = sm[0][lane] + sm[1][lane] + sm[2][lane] + sm[3][lane];
        float tq = qm[0][lane] + qm[1][lane] + qm[2][lane] + qm[3][lane];
        float* shard = bn_shard + (blockIdx.x & (NSHARD - 1)) * 128;
        atomicAdd(&shard[lane], ts);
        atomicAdd(&shard[64 + lane], tq);
    }
}

// reduce BN shards -> scale/shift; re-zero shards for the next layer
__global__ void k_bn_final(float* __restrict__ bn_shard, const float* __restrict__ gamma,
                           const float* __restrict__ beta, float* __restrict__ scale,
                           float* __restrict__ shift) {
    int t = threadIdx.x;
    if (t < 64) {
        float s = 0.f, q = 0.f;
        for (int i = 0; i < NSHARD; ++i) {
            s += bn_shard[i * 128 + t];
            q += bn_shard[i * 128 + 64 + t];
        }
        float mean = s * (1.0f / N_NODES);
        float var = q * (1.0f / N_NODES) - mean * mean;
        float sc = gamma[t] * rsqrtf(var + BN_EPS);
        scale[t] = sc;
        shift[t] = beta[t] - mean * sc;
    }
    __syncthreads();
    for (int i = t; i < NSHARD * 128; i += 256) bn_shard[i] = 0.f;
}

// ---------------------------------------------------------------------------
__global__ __launch_bounds__(256) void k_pool(const float* __restrict__ a2,
                                              const float* __restrict__ scale,
                                              const float* __restrict__ shift,
                                              const int* __restrict__ batch,
                                              float* __restrict__ pooled,
                                              float* __restrict__ pcnt) {
    int t = threadIdx.x;
    int c = t & 63;
    int rg = t >> 6;
    int base = blockIdx.x * 1024;
    float sc = scale[c], sh = shift[c];
    int gcur = -1;
    float acc = 0.f, cacc = 0.f;
    for (int i = rg; i < 1024; i += 4) {
        int v = base + i;
        if (v >= N_NODES) break;
        int g = batch[v];
        if (g != gcur) {
            if (gcur >= 0) {
                atomicAdd(&pooled[gcur * 64 + c], acc);
                if (c == 0) atomicAdd(&pcnt[gcur], cacc);
            }
            gcur = g;
            acc = 0.f;
            cacc = 0.f;
        }
        float h = fmaxf(sc * nt_f(a2 + (size_t)v * 64 + c) + sh, 0.f);
        acc += h;
        cacc += 1.f;
    }
    if (gcur >= 0) {
        atomicAdd(&pooled[gcur * 64 + c], acc);
        if (c == 0) atomicAdd(&pcnt[gcur], cacc);
    }
}

__global__ void k_out(const float* __restrict__ pooled, const float* __restrict__ pcnt,
                      const float* __restrict__ Wout, const float* __restrict__ bout,
                      float* __restrict__ out) {
    int g = threadIdx.x;
    if (g < N_GRAPHS) {
        float cnt = fmaxf(pcnt[g], 1.0f);
        float s = 0.f;
        for (int c = 0; c < 64; ++c) s += pooled[g * 64 + c] * Wout[c];
        out[g] = s / cnt + bout[0];
    }
}

// ---------------------------------------------------------------------------
extern "C" void kernel_launch(void* const* d_in, const int* in_sizes, int n_in,
                              void* d_out, int out_size, void* d_ws, size_t ws_size,
                              hipStream_t stream) {
    const float* x    = (const float*)d_in[0];
    const int*   ei   = (const int*)d_in[1];
    const float* ew   = (const float*)d_in[2];
    const int*   batch= (const int*)d_in[3];
    const float* W1   = (const float*)d_in[4];
    const float* b1   = (const float*)d_in[5];
    const float* W2   = (const float*)d_in[6];
    const float* b2   = (const float*)d_in[7];
    const float* g1   = (const float*)d_in[8];
    const float* be1  = (const float*)d_in[9];
    const float* g2   = (const float*)d_in[10];
    const float* be2  = (const float*)d_in[11];
    const float* Wout = (const float*)d_in[12];
    const float* bout = (const float*)d_in[13];
    float* out = (float*)d_out;

    char* w = (char*)d_ws;
    size_t o = 0;
    auto alloc = [&](size_t bytes) -> void* {
        void* p = w + o;
        o = (o + bytes + 255) & ~(size_t)255;
        return p;
    };
    int*   cnt2    = (int*)alloc(NCNT * 4);
    int*   soff    = (int*)alloc((NCNT + 1) * 4);
    int*   cur     = (int*)alloc(NCNT * 4);
    int*   nptr    = (int*)alloc((N_NODES + 1) * 4);
    float* dinv    = (float*)alloc(N_NODES * 4);
    float* bnshard = (float*)alloc(NSHARD * 128 * 4);
    float* scale1  = (float*)alloc(64 * 4);
    float* shift1  = (float*)alloc(64 * 4);
    float* scale2  = (float*)alloc(64 * 4);
    float* shift2  = (float*)alloc(64 * 4);
    float* pooled  = (float*)alloc(N_GRAPHS * 64 * 4);
    float* pcnt    = (float*)alloc(N_GRAPHS * 4);
    uint2* ebuf2   = (uint2*)alloc((size_t)N_EDGES * 8);
    float* bufA    = (float*)alloc((size_t)N_NODES * 64 * 4);
    float* bufB    = (float*)alloc((size_t)N_NODES * 64 * 4);
    // ebuf (unsorted, bucket-grouped) is dead before GEMM1 writes bufA: alias them.
    uint2* ebuf    = (uint2*)bufA;
    if (o > ws_size) return;

    (void)hipMemsetAsync(cnt2, 0, NCNT * 4, stream);
    (void)hipMemsetAsync(bnshard, 0, NSHARD * 128 * 4, stream);
    (void)hipMemsetAsync(pooled, 0, N_GRAPHS * 64 * 4, stream);
    (void)hipMemsetAsync(pcnt, 0, N_GRAPHS * 4, stream);

    k_count<<<BIN_BLOCKS, 256, 0, stream>>>(ei, cnt2);
    k_scan6k<<<1, 256, 0, stream>>>(cnt2, soff, cur, nptr);
    k_bin<<<BIN_BLOCKS, 256, 0, stream>>>(ei, ew, cur, ebuf);
    k_degb<<<NBUCK, 256, 0, stream>>>(ebuf, soff, dinv);
    k_sortnorm<<<NBUCK, 256, 0, stream>>>(ebuf, soff, dinv, ebuf2, nptr);

    // layer 1
    k_gemm<128, false><<<(N_NODES + 127) / 128, 256, 0, stream>>>(x, W1, nullptr, nullptr, bufA);
    k_agg<<<(N_NODES + 31) / 32, 256, 0, stream>>>(bufA, ebuf2, nptr, dinv, b1, bufB, bnshard);
    k_bn_final<<<1, 256, 0, stream>>>(bnshard, g1, be1, scale1, shift1);

    // layer 2
    k_gemm<64, true><<<(N_NODES + 127) / 128, 256, 0, stream>>>(bufB, W2, scale1, shift1, bufA);
    k_agg<<<(N_NODES + 31) / 32, 256, 0, stream>>>(bufA, ebuf2, nptr, dinv, b2, bufB, bnshard);
    k_bn_final<<<1, 256, 0, stream>>>(bnshard, g2, be2, scale2, shift2);

    // pool + output
    k_pool<<<(N_NODES + 1023) / 1024, 256, 0, stream>>>(bufB, scale2, shift2, batch, pooled, pcnt);
    k_out<<<1, 64, 0, stream>>>(pooled, pcnt, Wout, bout, out);
}

// Round 9
// 665.872 us; speedup vs baseline: 1.5842x; 1.0439x over previous
//
#include <hip/hip_runtime.h>
#include <stdint.h>

#define N_NODES 100000
#define N_EDGES 3200000
#define IN_DIM 128
#define HID 64
#define N_GRAPHS 64
#define BN_EPS 1e-5f
#define NSHARD 16
#define BUCK_SH 7
#define BUCK_SZ 128
#define NBUCK ((N_NODES + BUCK_SZ - 1) / BUCK_SZ)   // 782
#define NCNT (NBUCK * 8)                             // 6256
#define BINB_EDGES 4096                              // edges per binning block
#define BIN_BLOCKS ((N_EDGES + BINB_EDGES - 1) / BINB_EDGES)  // 782
#define EDGE_CAP 6016                                // LDS edge stage (mean 4092)

// __builtin_nontemporal_load needs native (ext_vector) types, not HIP structs.
typedef float vf4 __attribute__((ext_vector_type(4)));
typedef int   vi4 __attribute__((ext_vector_type(4)));
typedef unsigned vu2 __attribute__((ext_vector_type(2)));
typedef _Float16 vh4 __attribute__((ext_vector_type(4)));

__device__ __forceinline__ float4 nt_f4(const float* p) {
    vf4 v = __builtin_nontemporal_load((const vf4*)p);
    return make_float4(v.x, v.y, v.z, v.w);
}
__device__ __forceinline__ int4 nt_i4(const int* p) {
    vi4 v = __builtin_nontemporal_load((const vi4*)p);
    return make_int4(v.x, v.y, v.z, v.w);
}
__device__ __forceinline__ uint2 nt_u2(const uint2* p) {
    vu2 v = __builtin_nontemporal_load((const vu2*)p);
    return make_uint2(v.x, v.y);
}
__device__ __forceinline__ vh4 nt_h4(const _Float16* p) {
    return __builtin_nontemporal_load((const vh4*)p);
}

// ---------------------------------------------------------------------------
// block-aggregated count: LDS histogram per block (4096 edges), then ONE
// global atomic per non-empty (bucket, s). s = blockIdx&7 = XCD id.
__global__ __launch_bounds__(256) void k_count(const int* __restrict__ ei,
                                               int* __restrict__ cnt2) {
    __shared__ int hist[NBUCK];
    int b = blockIdx.x, t = threadIdx.x;
    int s = b & 7;
    int base = b * BINB_EDGES;
    int n = min(BINB_EDGES, N_EDGES - base);
    for (int i = t; i < NBUCK; i += 256) hist[i] = 0;
    __syncthreads();
#pragma unroll
    for (int k = 0; k < 4; ++k) {
        int ch = t + 256 * k;
        if (4 * ch < n) {
            int4 c4 = nt_i4(ei + N_EDGES + base + 4 * ch);
            atomicAdd(&hist[c4.x >> BUCK_SH], 1);
            atomicAdd(&hist[c4.y >> BUCK_SH], 1);
            atomicAdd(&hist[c4.z >> BUCK_SH], 1);
            atomicAdd(&hist[c4.w >> BUCK_SH], 1);
        }
    }
    __syncthreads();
    for (int j = t; j < NBUCK; j += 256) {
        int h = hist[j];
        if (h > 0) atomicAdd(&cnt2[(j << 3) + s], h);
    }
}

// single-block exclusive scan of cnt2[6256] -> soff[6257]; init cursors; nptr tail
__global__ void k_scan6k(const int* __restrict__ cnt2, int* __restrict__ soff,
                         int* __restrict__ cur, int* __restrict__ nptr) {
    __shared__ int parts[256];
    int t = threadIdx.x;
    int s = 0;
    for (int i = 0; i < 25; ++i) {
        int idx = t * 25 + i;
        if (idx < NCNT) s += cnt2[idx];
    }
    parts[t] = s;
    __syncthreads();
    for (int off = 1; off < 256; off <<= 1) {
        int x = (t >= off) ? parts[t - off] : 0;
        __syncthreads();
        parts[t] += x;
        __syncthreads();
    }
    int run = (t > 0) ? parts[t - 1] : 0;
    for (int i = 0; i < 25; ++i) {
        int idx = t * 25 + i;
        if (idx < NCNT) {
            soff[idx] = run;
            cur[idx] = run;
            run += cnt2[idx];
        }
    }
    if (t == 255) soff[NCNT] = parts[255];
    if (t == 0) nptr[N_NODES] = N_EDGES;
}

// block-aggregated bin: stage 4096 edges in LDS, histogram, reserve one global
// range per non-empty bucket, scatter from LDS (round-8 structure, proven).
__global__ __launch_bounds__(256) void k_bin(const int* __restrict__ ei,
                                             const float* __restrict__ ew,
                                             int* __restrict__ cur,
                                             uint2* __restrict__ ebuf) {
    __shared__ uint2 sed[BINB_EDGES];
    __shared__ unsigned short sbk[BINB_EDGES];
    __shared__ int hist[NBUCK];
    int b = blockIdx.x, t = threadIdx.x;
    int s = b & 7;
    int base = b * BINB_EDGES;
    int n = min(BINB_EDGES, N_EDGES - base);
    for (int i = t; i < NBUCK; i += 256) hist[i] = 0;
    __syncthreads();
#pragma unroll
    for (int k = 0; k < 4; ++k) {
        int ch = t + 256 * k;
        if (4 * ch < n) {
            int4 r4 = nt_i4(ei + base + 4 * ch);
            int4 c4 = nt_i4(ei + N_EDGES + base + 4 * ch);
            float4 w4 = nt_f4(ew + base + 4 * ch);
            int rr[4] = {r4.x, r4.y, r4.z, r4.w};
            int cc[4] = {c4.x, c4.y, c4.z, c4.w};
            float ww[4] = {w4.x, w4.y, w4.z, w4.w};
#pragma unroll
            for (int u = 0; u < 4; ++u) {
                int li = 4 * ch + u;
                sed[li] = make_uint2(
                    (unsigned)(rr[u] | ((cc[u] & (BUCK_SZ - 1)) << 17)),
                    __float_as_uint(ww[u]));
                int bk = cc[u] >> BUCK_SH;
                sbk[li] = (unsigned short)bk;
                atomicAdd(&hist[bk], 1);
            }
        }
    }
    __syncthreads();
    for (int j = t; j < NBUCK; j += 256) {
        int h = hist[j];
        if (h > 0) hist[j] = atomicAdd(&cur[(j << 3) + s], h);
    }
    __syncthreads();
    for (int i = t; i < n; i += 256) {
        int bk = sbk[i];
        int pos = atomicAdd(&hist[bk], 1);
        ebuf[pos] = sed[i];
    }
}

// per-bucket weighted degree -> dinv (bucket-local edges, LDS atomics only)
__global__ __launch_bounds__(256) void k_degb(const uint2* __restrict__ ebuf,
                                              const int* __restrict__ soff,
                                              float* __restrict__ dinv) {
    __shared__ float dacc[BUCK_SZ];
    int b = blockIdx.x, t = threadIdx.x;
    if (t < BUCK_SZ) dacc[t] = 0.f;
    __syncthreads();
    int beg = soff[b << 3], end = soff[(b << 3) + 8];
    for (int i = beg + t; i < end; i += 256) {
        uint2 u = nt_u2(ebuf + i);
        atomicAdd(&dacc[u.x >> 17], __uint_as_float(u.y));
    }
    __syncthreads();
    int node = b * BUCK_SZ + t;
    if (t < BUCK_SZ && node < N_NODES) dinv[node] = rsqrtf(dacc[t] + 1.0f);
}

// per-bucket counting sort by local dest + norm (dinv complete before launch)
__global__ __launch_bounds__(256) void k_sortnorm(const uint2* __restrict__ ebuf,
                                                  const int* __restrict__ soff,
                                                  const float* __restrict__ dinv,
                                                  uint2* __restrict__ ebuf2,
                                                  int* __restrict__ nptr) {
    __shared__ uint2 se[EDGE_CAP];
    __shared__ float sdi[BUCK_SZ];
    __shared__ int scnt[BUCK_SZ];
    __shared__ int scur[BUCK_SZ];
    int b = blockIdx.x, t = threadIdx.x;
    if (t < BUCK_SZ) {
        scnt[t] = 0;
        int node = b * BUCK_SZ + t;
        sdi[t] = (node < N_NODES) ? dinv[node] : 0.f;
    }
    __syncthreads();
    int beg = soff[b << 3], end = soff[(b << 3) + 8];
    int n = end - beg;
    bool fit = (n <= EDGE_CAP);
    for (int i = t; i < n; i += 256) {
        uint2 u = nt_u2(ebuf + beg + i);
        if (fit) se[i] = u;
        atomicAdd(&scnt[u.x >> 17], 1);
    }
    __syncthreads();
    for (int off = 1; off < BUCK_SZ; off <<= 1) {
        int x = 0;
        if (t < BUCK_SZ && t >= off) x = scnt[t - off];
        __syncthreads();
        if (t < BUCK_SZ) scnt[t] += x;
        __syncthreads();
    }
    if (t < BUCK_SZ) {
        int excl = (t > 0) ? scnt[t - 1] : 0;
        scur[t] = beg + excl;
        int node = b * BUCK_SZ + t;
        if (node < N_NODES) nptr[node] = beg + excl;
    }
    __syncthreads();
    for (int i = t; i < n; i += 256) {
        uint2 u = fit ? se[i] : nt_u2(ebuf + beg + i);
        int r = u.x & 131071;
        int cl = u.x >> 17;
        float nm = dinv[r] * __uint_as_float(u.y) * sdi[cl];
        int p = atomicAdd(&scur[cl], 1);
        ebuf2[p] = make_uint2((unsigned)r, __float_as_uint(nm));
    }
}

// ---------------------------------------------------------------------------
// GEMM: out[n][c] = sum_k in[n][k]*W[k][c]; fp16 output.
// BNH: input is fp16 with fused BN+ReLU (layer 2); else f32 input (layer 1).
template <int K, bool BNH>
__global__ __launch_bounds__(256) void k_gemm(const void* __restrict__ in_,
                                              const float* __restrict__ W,
                                              const float* __restrict__ scale,
                                              const float* __restrict__ shift,
                                              _Float16* __restrict__ out) {
    __shared__ float ws[K * 64];
    __shared__ float xs[32 * 132];
    __shared__ float ssc[64], ssh[64];
    int t = threadIdx.x;
    int nbase = blockIdx.x * 128;

#pragma unroll
    for (int i = 0; i < K / 16; ++i) {
        int idx = t + 256 * i;
        ((float4*)ws)[idx] = ((const float4*)W)[idx];
    }
    if (BNH && t < 64) { ssc[t] = scale[t]; ssh[t] = shift[t]; }

    int cg = t & 15;
    int ng = t >> 4;
    float acc[8][4];
#pragma unroll
    for (int i = 0; i < 8; ++i)
#pragma unroll
        for (int j = 0; j < 4; ++j) acc[i][j] = 0.f;

    for (int k0 = 0; k0 < K; k0 += 32) {
        __syncthreads();
#pragma unroll
        for (int i = 0; i < 4; ++i) {
            int idx = t + 256 * i;
            int row = idx >> 3;
            int kq = idx & 7;
            int node = nbase + row;
            float vv[4] = {0.f, 0.f, 0.f, 0.f};
            if (node < N_NODES) {
                if (BNH) {
                    vh4 v = nt_h4((const _Float16*)in_ + (size_t)node * K + k0 + kq * 4);
                    vv[0] = (float)v.x; vv[1] = (float)v.y;
                    vv[2] = (float)v.z; vv[3] = (float)v.w;
                } else {
                    float4 v = nt_f4((const float*)in_ + (size_t)node * K + k0 + kq * 4);
                    vv[0] = v.x; vv[1] = v.y; vv[2] = v.z; vv[3] = v.w;
                }
            }
#pragma unroll
            for (int u = 0; u < 4; ++u) {
                float val = vv[u];
                if (BNH) {
                    int k = k0 + kq * 4 + u;
                    val = fmaxf(ssc[k] * val + ssh[k], 0.f);
                }
                xs[(kq * 4 + u) * 132 + row] = val;
            }
        }
        __syncthreads();
#pragma unroll
        for (int k = 0; k < 32; ++k) {
            float4 wv = *(const float4*)(ws + (k0 + k) * 64 + cg * 4);
            float4 xa = *(const float4*)(xs + k * 132 + ng * 8);
            float4 xb = *(const float4*)(xs + k * 132 + ng * 8 + 4);
            float xv[8] = {xa.x, xa.y, xa.z, xa.w, xb.x, xb.y, xb.z, xb.w};
            float wvv[4] = {wv.x, wv.y, wv.z, wv.w};
#pragma unroll
            for (int i = 0; i < 8; ++i)
#pragma unroll
                for (int j = 0; j < 4; ++j) acc[i][j] += xv[i] * wvv[j];
        }
    }
#pragma unroll
    for (int i = 0; i < 8; ++i) {
        int node = nbase + ng * 8 + i;
        if (node < N_NODES) {
            vh4 o;
            o.x = (_Float16)acc[i][0]; o.y = (_Float16)acc[i][1];
            o.z = (_Float16)acc[i][2]; o.w = (_Float16)acc[i][3];
            *(vh4*)(out + (size_t)node * 64 + cg * 4) = o;
        }
    }
}

// ---------------------------------------------------------------------------
// CSR gather-aggregation: wave per node (lane=channel), f32 register accum,
// fp16 gather rows (128 B/row). Fused self-loop, bias, BN partials.
__global__ __launch_bounds__(256) void k_agg(const _Float16* __restrict__ hin,
                                             const uint2* __restrict__ ebuf2,
                                             const int* __restrict__ nptr,
                                             const float* __restrict__ dinv,
                                             const float* __restrict__ bias,
                                             _Float16* __restrict__ hout,
                                             float* __restrict__ bn_shard) {
    int wave = threadIdx.x >> 6;
    int lane = threadIdx.x & 63;
    float s = 0.f, q = 0.f;
    float bl = bias[lane];
    int vbase = blockIdx.x * 32 + wave * 8;
    for (int vi = 0; vi < 8; ++vi) {
        int v = vbase + vi;
        if (v >= N_NODES) break;
        int beg = nptr[v], end = nptr[v + 1];
        float acc = 0.f;
        int j = beg;
        for (; j + 8 <= end; j += 8) {
            float fv[8], fn[8];
#pragma unroll
            for (int u = 0; u < 8; ++u) {
                uint2 e = nt_u2(ebuf2 + j + u);
                fn[u] = __uint_as_float(e.y);
                fv[u] = (float)hin[((size_t)e.x << 6) + lane];
            }
#pragma unroll
            for (int u = 0; u < 8; ++u) acc = fmaf(fn[u], fv[u], acc);
        }
        for (; j < end; ++j) {
            uint2 e = nt_u2(ebuf2 + j);
            acc = fmaf(__uint_as_float(e.y), (float)hin[((size_t)e.x << 6) + lane], acc);
        }
        float dv = dinv[v];
        acc = fmaf(dv * dv, (float)hin[((size_t)v << 6) + lane], acc);
        acc += bl;
        hout[((size_t)v << 6) + lane] = (_Float16)acc;
        s += acc;
        q += acc * acc;
    }
    __shared__ float sm[4][64], qm[4][64];
    sm[wave][lane] = s;
    qm[wave][lane] = q;
    __syncthreads();
    if (wave == 0) {
        float ts = sm[0][lane] + sm[1][lane] + sm[2][lane] + sm[3][lane];
        float tq = qm[0][lane] + qm[1][lane] + qm[2][lane] + qm[3][lane];
        float* shard = bn_shard + (blockIdx.x & (NSHARD - 1)) * 128;
        atomicAdd(&shard[lane], ts);
        atomicAdd(&shard[64 + lane], tq);
    }
}

// reduce BN shards -> scale/shift; re-zero shards for the next layer
__global__ void k_bn_final(float* __restrict__ bn_shard, const float* __restrict__ gamma,
                           const float* __restrict__ beta, float* __restrict__ scale,
                           float* __restrict__ shift) {
    int t = threadIdx.x;
    if (t < 64) {
        float s = 0.f, q = 0.f;
        for (int i = 0; i < NSHARD; ++i) {
            s += bn_shard[i * 128 + t];
            q += bn_shard[i * 128 + 64 + t];
        }
        float mean = s * (1.0f / N_NODES);
        float var = q * (1.0f / N_NODES) - mean * mean;
        float sc = gamma[t] * rsqrtf(var + BN_EPS);
        scale[t] = sc;
        shift[t] = beta[t] - mean * sc;
    }
    __syncthreads();
    for (int i = t; i < NSHARD * 128; i += 256) bn_shard[i] = 0.f;
}

// ---------------------------------------------------------------------------
__global__ __launch_bounds__(256) void k_pool(const _Float16* __restrict__ a2,
                                              const float* __restrict__ scale,
                                              const float* __restrict__ shift,
                                              const int* __restrict__ batch,
                                              float* __restrict__ pooled,
                                              float* __restrict__ pcnt) {
    int t = threadIdx.x;
    int c = t & 63;
    int rg = t >> 6;
    int base = blockIdx.x * 1024;
    float sc = scale[c], sh = shift[c];
    int gcur = -1;
    float acc = 0.f, cacc = 0.f;
    for (int i = rg; i < 1024; i += 4) {
        int v = base + i;
        if (v >= N_NODES) break;
        int g = batch[v];
        if (g != gcur) {
            if (gcur >= 0) {
                atomicAdd(&pooled[gcur * 64 + c], acc);
                if (c == 0) atomicAdd(&pcnt[gcur], cacc);
            }
            gcur = g;
            acc = 0.f;
            cacc = 0.f;
        }
        float h = fmaxf(sc * (float)a2[(size_t)v * 64 + c] + sh, 0.f);
        acc += h;
        cacc += 1.f;
    }
    if (gcur >= 0) {
        atomicAdd(&pooled[gcur * 64 + c], acc);
        if (c == 0) atomicAdd(&pcnt[gcur], cacc);
    }
}

__global__ void k_out(const float* __restrict__ pooled, const float* __restrict__ pcnt,
                      const float* __restrict__ Wout, const float* __restrict__ bout,
                      float* __restrict__ out) {
    int g = threadIdx.x;
    if (g < N_GRAPHS) {
        float cnt = fmaxf(pcnt[g], 1.0f);
        float s = 0.f;
        for (int c = 0; c < 64; ++c) s += pooled[g * 64 + c] * Wout[c];
        out[g] = s / cnt + bout[0];
    }
}

// ---------------------------------------------------------------------------
extern "C" void kernel_launch(void* const* d_in, const int* in_sizes, int n_in,
                              void* d_out, int out_size, void* d_ws, size_t ws_size,
                              hipStream_t stream) {
    const float* x    = (const float*)d_in[0];
    const int*   ei   = (const int*)d_in[1];
    const float* ew   = (const float*)d_in[2];
    const int*   batch= (const int*)d_in[3];
    const float* W1   = (const float*)d_in[4];
    const float* b1   = (const float*)d_in[5];
    const float* W2   = (const float*)d_in[6];
    const float* b2   = (const float*)d_in[7];
    const float* g1   = (const float*)d_in[8];
    const float* be1  = (const float*)d_in[9];
    const float* g2   = (const float*)d_in[10];
    const float* be2  = (const float*)d_in[11];
    const float* Wout = (const float*)d_in[12];
    const float* bout = (const float*)d_in[13];
    float* out = (float*)d_out;

    char* w = (char*)d_ws;
    size_t o = 0;
    auto alloc = [&](size_t bytes) -> void* {
        void* p = w + o;
        o = (o + bytes + 255) & ~(size_t)255;
        return p;
    };
    int*   cnt2    = (int*)alloc(NCNT * 4);
    int*   soff    = (int*)alloc((NCNT + 1) * 4);
    int*   cur     = (int*)alloc(NCNT * 4);
    int*   nptr    = (int*)alloc((N_NODES + 1) * 4);
    float* dinv    = (float*)alloc(N_NODES * 4);
    float* bnshard = (float*)alloc(NSHARD * 128 * 4);
    float* scale1  = (float*)alloc(64 * 4);
    float* shift1  = (float*)alloc(64 * 4);
    float* scale2  = (float*)alloc(64 * 4);
    float* shift2  = (float*)alloc(64 * 4);
    float* pooled  = (float*)alloc(N_GRAPHS * 64 * 4);
    float* pcnt    = (float*)alloc(N_GRAPHS * 4);
    uint2* ebuf2   = (uint2*)alloc((size_t)N_EDGES * 8);
    // 25.6 MB region triple-use: ebuf (binning scratch, dead after k_sortnorm)
    // then two fp16 node buffers HA/HB (12.8 MB each), written only after.
    uint2* ebuf    = (uint2*)alloc((size_t)N_EDGES * 8);
    _Float16* bufHA = (_Float16*)ebuf;
    _Float16* bufHB = bufHA + (size_t)N_NODES * 64;
    if (o > ws_size) return;

    (void)hipMemsetAsync(cnt2, 0, NCNT * 4, stream);
    (void)hipMemsetAsync(bnshard, 0, NSHARD * 128 * 4, stream);
    (void)hipMemsetAsync(pooled, 0, N_GRAPHS * 64 * 4, stream);
    (void)hipMemsetAsync(pcnt, 0, N_GRAPHS * 4, stream);

    k_count<<<BIN_BLOCKS, 256, 0, stream>>>(ei, cnt2);
    k_scan6k<<<1, 256, 0, stream>>>(cnt2, soff, cur, nptr);
    k_bin<<<BIN_BLOCKS, 256, 0, stream>>>(ei, ew, cur, ebuf);
    k_degb<<<NBUCK, 256, 0, stream>>>(ebuf, soff, dinv);
    k_sortnorm<<<NBUCK, 256, 0, stream>>>(ebuf, soff, dinv, ebuf2, nptr);

    // layer 1: x (f32) -> h1 (fp16) -> a1 (fp16) + BN1 stats
    k_gemm<128, false><<<(N_NODES + 127) / 128, 256, 0, stream>>>(x, W1, nullptr, nullptr, bufHA);
    k_agg<<<(N_NODES + 31) / 32, 256, 0, stream>>>(bufHA, ebuf2, nptr, dinv, b1, bufHB, bnshard);
    k_bn_final<<<1, 256, 0, stream>>>(bnshard, g1, be1, scale1, shift1);

    // layer 2: a1 (fp16, fused BN+ReLU) -> h2 (fp16) -> a2 (fp16) + BN2 stats
    k_gemm<64, true><<<(N_NODES + 127) / 128, 256, 0, stream>>>(bufHB, W2, scale1, shift1, bufHA);
    k_agg<<<(N_NODES + 31) / 32, 256, 0, stream>>>(bufHA, ebuf2, nptr, dinv, b2, bufHB, bnshard);
    k_bn_final<<<1, 256, 0, stream>>>(bnshard, g2, be2, scale2, shift2);

    // pool (fused BN2+ReLU) + output
    k_pool<<<(N_NODES + 1023) / 1024, 256, 0, stream>>>(bufHB, scale2, shift2, batch, pooled, pcnt);
    k_out<<<1, 64, 0, stream>>>(pooled, pcnt, Wout, bout, out);
}

// Round 10
// 530.607 us; speedup vs baseline: 1.9880x; 1.2549x over previous
//
#include <hip/hip_runtime.h>
#include <stdint.h>

#define N_NODES 100000
#define N_EDGES 3200000
#define IN_DIM 128
#define HID 64
#define N_GRAPHS 64
#define BN_EPS 1e-5f
#define NSHARD 16
#define BUCK_SH 7
#define BUCK_SZ 128
#define NBUCK ((N_NODES + BUCK_SZ - 1) / BUCK_SZ)   // 782
#define NCNT (NBUCK * 8)                             // 6256
#define BINB_EDGES 4096                              // edges per binning block
#define BIN_BLOCKS ((N_EDGES + BINB_EDGES - 1) / BINB_EDGES)  // 782
#define EDGE_CAP 6016                                // LDS edge stage (mean 4092)
#define AGG_CAP 2048                                 // agg block edge stage (mean 1024)

// __builtin_nontemporal_load needs native (ext_vector) types, not HIP structs.
typedef float vf4 __attribute__((ext_vector_type(4)));
typedef int   vi4 __attribute__((ext_vector_type(4)));
typedef unsigned vu2 __attribute__((ext_vector_type(2)));
typedef _Float16 vh4 __attribute__((ext_vector_type(4)));

__device__ __forceinline__ float4 nt_f4(const float* p) {
    vf4 v = __builtin_nontemporal_load((const vf4*)p);
    return make_float4(v.x, v.y, v.z, v.w);
}
__device__ __forceinline__ int4 nt_i4(const int* p) {
    vi4 v = __builtin_nontemporal_load((const vi4*)p);
    return make_int4(v.x, v.y, v.z, v.w);
}
__device__ __forceinline__ uint2 nt_u2(const uint2* p) {
    vu2 v = __builtin_nontemporal_load((const vu2*)p);
    return make_uint2(v.x, v.y);
}
__device__ __forceinline__ vh4 nt_h4(const _Float16* p) {
    return __builtin_nontemporal_load((const vh4*)p);
}

// ---------------------------------------------------------------------------
// block-aggregated count: LDS histogram per block (4096 edges), then ONE
// global atomic per non-empty (bucket, s). s = blockIdx&7 = XCD id.
__global__ __launch_bounds__(256) void k_count(const int* __restrict__ ei,
                                               int* __restrict__ cnt2) {
    __shared__ int hist[NBUCK];
    int b = blockIdx.x, t = threadIdx.x;
    int s = b & 7;
    int base = b * BINB_EDGES;
    int n = min(BINB_EDGES, N_EDGES - base);
    for (int i = t; i < NBUCK; i += 256) hist[i] = 0;
    __syncthreads();
#pragma unroll
    for (int k = 0; k < 4; ++k) {
        int ch = t + 256 * k;
        if (4 * ch < n) {
            int4 c4 = nt_i4(ei + N_EDGES + base + 4 * ch);
            atomicAdd(&hist[c4.x >> BUCK_SH], 1);
            atomicAdd(&hist[c4.y >> BUCK_SH], 1);
            atomicAdd(&hist[c4.z >> BUCK_SH], 1);
            atomicAdd(&hist[c4.w >> BUCK_SH], 1);
        }
    }
    __syncthreads();
    for (int j = t; j < NBUCK; j += 256) {
        int h = hist[j];
        if (h > 0) atomicAdd(&cnt2[(j << 3) + s], h);
    }
}

// single-block exclusive scan of cnt2[6256] -> soff[6257]; init cursors; nptr tail
__global__ void k_scan6k(const int* __restrict__ cnt2, int* __restrict__ soff,
                         int* __restrict__ cur, int* __restrict__ nptr) {
    __shared__ int parts[256];
    int t = threadIdx.x;
    int s = 0;
    for (int i = 0; i < 25; ++i) {
        int idx = t * 25 + i;
        if (idx < NCNT) s += cnt2[idx];
    }
    parts[t] = s;
    __syncthreads();
    for (int off = 1; off < 256; off <<= 1) {
        int x = (t >= off) ? parts[t - off] : 0;
        __syncthreads();
        parts[t] += x;
        __syncthreads();
    }
    int run = (t > 0) ? parts[t - 1] : 0;
    for (int i = 0; i < 25; ++i) {
        int idx = t * 25 + i;
        if (idx < NCNT) {
            soff[idx] = run;
            cur[idx] = run;
            run += cnt2[idx];
        }
    }
    if (t == 255) soff[NCNT] = parts[255];
    if (t == 0) nptr[N_NODES] = N_EDGES;
}

// block-aggregated bin: stage 4096 edges in LDS, histogram, reserve one global
// range per non-empty bucket, scatter from LDS (round-8 structure, proven).
__global__ __launch_bounds__(256) void k_bin(const int* __restrict__ ei,
                                             const float* __restrict__ ew,
                                             int* __restrict__ cur,
                                             uint2* __restrict__ ebuf) {
    __shared__ uint2 sed[BINB_EDGES];
    __shared__ unsigned short sbk[BINB_EDGES];
    __shared__ int hist[NBUCK];
    int b = blockIdx.x, t = threadIdx.x;
    int s = b & 7;
    int base = b * BINB_EDGES;
    int n = min(BINB_EDGES, N_EDGES - base);
    for (int i = t; i < NBUCK; i += 256) hist[i] = 0;
    __syncthreads();
#pragma unroll
    for (int k = 0; k < 4; ++k) {
        int ch = t + 256 * k;
        if (4 * ch < n) {
            int4 r4 = nt_i4(ei + base + 4 * ch);
            int4 c4 = nt_i4(ei + N_EDGES + base + 4 * ch);
            float4 w4 = nt_f4(ew + base + 4 * ch);
            int rr[4] = {r4.x, r4.y, r4.z, r4.w};
            int cc[4] = {c4.x, c4.y, c4.z, c4.w};
            float ww[4] = {w4.x, w4.y, w4.z, w4.w};
#pragma unroll
            for (int u = 0; u < 4; ++u) {
                int li = 4 * ch + u;
                sed[li] = make_uint2(
                    (unsigned)(rr[u] | ((cc[u] & (BUCK_SZ - 1)) << 17)),
                    __float_as_uint(ww[u]));
                int bk = cc[u] >> BUCK_SH;
                sbk[li] = (unsigned short)bk;
                atomicAdd(&hist[bk], 1);
            }
        }
    }
    __syncthreads();
    for (int j = t; j < NBUCK; j += 256) {
        int h = hist[j];
        if (h > 0) hist[j] = atomicAdd(&cur[(j << 3) + s], h);
    }
    __syncthreads();
    for (int i = t; i < n; i += 256) {
        int bk = sbk[i];
        int pos = atomicAdd(&hist[bk], 1);
        ebuf[pos] = sed[i];
    }
}

// per-bucket weighted degree -> dinv (bucket-local edges, LDS atomics only)
__global__ __launch_bounds__(256) void k_degb(const uint2* __restrict__ ebuf,
                                              const int* __restrict__ soff,
                                              float* __restrict__ dinv) {
    __shared__ float dacc[BUCK_SZ];
    int b = blockIdx.x, t = threadIdx.x;
    if (t < BUCK_SZ) dacc[t] = 0.f;
    __syncthreads();
    int beg = soff[b << 3], end = soff[(b << 3) + 8];
    for (int i = beg + t; i < end; i += 256) {
        uint2 u = nt_u2(ebuf + i);
        atomicAdd(&dacc[u.x >> 17], __uint_as_float(u.y));
    }
    __syncthreads();
    int node = b * BUCK_SZ + t;
    if (t < BUCK_SZ && node < N_NODES) dinv[node] = rsqrtf(dacc[t] + 1.0f);
}

// per-bucket counting sort by local dest + norm (dinv complete before launch)
__global__ __launch_bounds__(256) void k_sortnorm(const uint2* __restrict__ ebuf,
                                                  const int* __restrict__ soff,
                                                  const float* __restrict__ dinv,
                                                  uint2* __restrict__ ebuf2,
                                                  int* __restrict__ nptr) {
    __shared__ uint2 se[EDGE_CAP];
    __shared__ float sdi[BUCK_SZ];
    __shared__ int scnt[BUCK_SZ];
    __shared__ int scur[BUCK_SZ];
    int b = blockIdx.x, t = threadIdx.x;
    if (t < BUCK_SZ) {
        scnt[t] = 0;
        int node = b * BUCK_SZ + t;
        sdi[t] = (node < N_NODES) ? dinv[node] : 0.f;
    }
    __syncthreads();
    int beg = soff[b << 3], end = soff[(b << 3) + 8];
    int n = end - beg;
    bool fit = (n <= EDGE_CAP);
    for (int i = t; i < n; i += 256) {
        uint2 u = nt_u2(ebuf + beg + i);
        if (fit) se[i] = u;
        atomicAdd(&scnt[u.x >> 17], 1);
    }
    __syncthreads();
    for (int off = 1; off < BUCK_SZ; off <<= 1) {
        int x = 0;
        if (t < BUCK_SZ && t >= off) x = scnt[t - off];
        __syncthreads();
        if (t < BUCK_SZ) scnt[t] += x;
        __syncthreads();
    }
    if (t < BUCK_SZ) {
        int excl = (t > 0) ? scnt[t - 1] : 0;
        scur[t] = beg + excl;
        int node = b * BUCK_SZ + t;
        if (node < N_NODES) nptr[node] = beg + excl;
    }
    __syncthreads();
    for (int i = t; i < n; i += 256) {
        uint2 u = fit ? se[i] : nt_u2(ebuf + beg + i);
        int r = u.x & 131071;
        int cl = u.x >> 17;
        float nm = dinv[r] * __uint_as_float(u.y) * sdi[cl];
        int p = atomicAdd(&scur[cl], 1);
        ebuf2[p] = make_uint2((unsigned)r, __float_as_uint(nm));
    }
}

// ---------------------------------------------------------------------------
// GEMM: out[n][c] = sum_k in[n][k]*W[k][c]; fp16 output.
// BNH: input is fp16 with fused BN+ReLU (layer 2); else f32 input (layer 1).
template <int K, bool BNH>
__global__ __launch_bounds__(256) void k_gemm(const void* __restrict__ in_,
                                              const float* __restrict__ W,
                                              const float* __restrict__ scale,
                                              const float* __restrict__ shift,
                                              _Float16* __restrict__ out) {
    __shared__ float ws[K * 64];
    __shared__ float xs[32 * 132];
    __shared__ float ssc[64], ssh[64];
    int t = threadIdx.x;
    int nbase = blockIdx.x * 128;

#pragma unroll
    for (int i = 0; i < K / 16; ++i) {
        int idx = t + 256 * i;
        ((float4*)ws)[idx] = ((const float4*)W)[idx];
    }
    if (BNH && t < 64) { ssc[t] = scale[t]; ssh[t] = shift[t]; }

    int cg = t & 15;
    int ng = t >> 4;
    float acc[8][4];
#pragma unroll
    for (int i = 0; i < 8; ++i)
#pragma unroll
        for (int j = 0; j < 4; ++j) acc[i][j] = 0.f;

    for (int k0 = 0; k0 < K; k0 += 32) {
        __syncthreads();
#pragma unroll
        for (int i = 0; i < 4; ++i) {
            int idx = t + 256 * i;
            int row = idx >> 3;
            int kq = idx & 7;
            int node = nbase + row;
            float vv[4] = {0.f, 0.f, 0.f, 0.f};
            if (node < N_NODES) {
                if (BNH) {
                    vh4 v = nt_h4((const _Float16*)in_ + (size_t)node * K + k0 + kq * 4);
                    vv[0] = (float)v.x; vv[1] = (float)v.y;
                    vv[2] = (float)v.z; vv[3] = (float)v.w;
                } else {
                    float4 v = nt_f4((const float*)in_ + (size_t)node * K + k0 + kq * 4);
                    vv[0] = v.x; vv[1] = v.y; vv[2] = v.z; vv[3] = v.w;
                }
            }
#pragma unroll
            for (int u = 0; u < 4; ++u) {
                float val = vv[u];
                if (BNH) {
                    int k = k0 + kq * 4 + u;
                    val = fmaxf(ssc[k] * val + ssh[k], 0.f);
                }
                xs[(kq * 4 + u) * 132 + row] = val;
            }
        }
        __syncthreads();
#pragma unroll
        for (int k = 0; k < 32; ++k) {
            float4 wv = *(const float4*)(ws + (k0 + k) * 64 + cg * 4);
            float4 xa = *(const float4*)(xs + k * 132 + ng * 8);
            float4 xb = *(const float4*)(xs + k * 132 + ng * 8 + 4);
            float xv[8] = {xa.x, xa.y, xa.z, xa.w, xb.x, xb.y, xb.z, xb.w};
            float wvv[4] = {wv.x, wv.y, wv.z, wv.w};
#pragma unroll
            for (int i = 0; i < 8; ++i)
#pragma unroll
                for (int j = 0; j < 4; ++j) acc[i][j] += xv[i] * wvv[j];
        }
    }
#pragma unroll
    for (int i = 0; i < 8; ++i) {
        int node = nbase + ng * 8 + i;
        if (node < N_NODES) {
            vh4 o;
            o.x = (_Float16)acc[i][0]; o.y = (_Float16)acc[i][1];
            o.z = (_Float16)acc[i][2]; o.w = (_Float16)acc[i][3];
            *(vh4*)(out + (size_t)node * 64 + cg * 4) = o;
        }
    }
}

// ---------------------------------------------------------------------------
// CSR gather-aggregation v3: block stages its 32 nodes' contiguous edge metas
// in LDS (one coalesced pass), so the per-edge path is ds_read -> row gather
// with no VMEM->VMEM dependency chain; row gathers pile up many-deep.
// Wave per node (lane=channel), f32 accum, fused self-loop/bias/BN partials.
__global__ __launch_bounds__(256) void k_agg(const _Float16* __restrict__ hin,
                                             const uint2* __restrict__ ebuf2,
                                             const int* __restrict__ nptr,
                                             const float* __restrict__ dinv,
                                             const float* __restrict__ bias,
                                             _Float16* __restrict__ hout,
                                             float* __restrict__ bn_shard) {
    __shared__ uint2 sme[AGG_CAP];
    __shared__ float sm[4][64], qm[4][64];
    int b = blockIdx.x, t = threadIdx.x;
    int wave = t >> 6, lane = t & 63;
    int vbase0 = b * 32;                       // grid is exactly N_NODES/32
    int ebeg = nptr[vbase0];
    int eend = nptr[vbase0 + 32];
    int n = eend - ebeg;
    bool fit = (n <= AGG_CAP);
    if (fit) {
        for (int i = t; i < n; i += 256) sme[i] = nt_u2(ebuf2 + ebeg + i);
    }
    __syncthreads();

    float s = 0.f, q = 0.f;
    float bl = bias[lane];
    int vbase = vbase0 + wave * 8;
    for (int vi = 0; vi < 8; ++vi) {
        int v = vbase + vi;
        int beg = nptr[v], end = nptr[v + 1];
        float acc = 0.f;
        int j = beg;
        if (fit) {
            for (; j + 8 <= end; j += 8) {
                float fv[8], fn[8];
#pragma unroll
                for (int u = 0; u < 8; ++u) {
                    uint2 e = sme[j - ebeg + u];
                    fn[u] = __uint_as_float(e.y);
                    fv[u] = (float)hin[((size_t)e.x << 6) + lane];
                }
#pragma unroll
                for (int u = 0; u < 8; ++u) acc = fmaf(fn[u], fv[u], acc);
            }
            for (; j < end; ++j) {
                uint2 e = sme[j - ebeg];
                acc = fmaf(__uint_as_float(e.y),
                           (float)hin[((size_t)e.x << 6) + lane], acc);
            }
        } else {
            for (; j + 8 <= end; j += 8) {
                float fv[8], fn[8];
#pragma unroll
                for (int u = 0; u < 8; ++u) {
                    uint2 e = nt_u2(ebuf2 + j + u);
                    fn[u] = __uint_as_float(e.y);
                    fv[u] = (float)hin[((size_t)e.x << 6) + lane];
                }
#pragma unroll
                for (int u = 0; u < 8; ++u) acc = fmaf(fn[u], fv[u], acc);
            }
            for (; j < end; ++j) {
                uint2 e = nt_u2(ebuf2 + j);
                acc = fmaf(__uint_as_float(e.y),
                           (float)hin[((size_t)e.x << 6) + lane], acc);
            }
        }
        float dv = dinv[v];
        acc = fmaf(dv * dv, (float)hin[((size_t)v << 6) + lane], acc);
        acc += bl;
        hout[((size_t)v << 6) + lane] = (_Float16)acc;
        s += acc;
        q += acc * acc;
    }
    sm[wave][lane] = s;
    qm[wave][lane] = q;
    __syncthreads();
    if (wave == 0) {
        float ts = sm[0][lane] + sm[1][lane] + sm[2][lane] + sm[3][lane];
        float tq = qm[0][lane] + qm[1][lane] + qm[2][lane] + qm[3][lane];
        float* shard = bn_shard + (blockIdx.x & (NSHARD - 1)) * 128;
        atomicAdd(&shard[lane], ts);
        atomicAdd(&shard[64 + lane], tq);
    }
}

// reduce BN shards -> scale/shift; re-zero shards for the next layer
__global__ void k_bn_final(float* __restrict__ bn_shard, const float* __restrict__ gamma,
                           const float* __restrict__ beta, float* __restrict__ scale,
                           float* __restrict__ shift) {
    int t = threadIdx.x;
    if (t < 64) {
        float s = 0.f, q = 0.f;
        for (int i = 0; i < NSHARD; ++i) {
            s += bn_shard[i * 128 + t];
            q += bn_shard[i * 128 + 64 + t];
        }
        float mean = s * (1.0f / N_NODES);
        float var = q * (1.0f / N_NODES) - mean * mean;
        float sc = gamma[t] * rsqrtf(var + BN_EPS);
        scale[t] = sc;
        shift[t] = beta[t] - mean * sc;
    }
    __syncthreads();
    for (int i = t; i < NSHARD * 128; i += 256) bn_shard[i] = 0.f;
}

// ---------------------------------------------------------------------------
__global__ __launch_bounds__(256) void k_pool(const _Float16* __restrict__ a2,
                                              const float* __restrict__ scale,
                                              const float* __restrict__ shift,
                                              const int* __restrict__ batch,
                                              float* __restrict__ pooled,
                                              float* __restrict__ pcnt) {
    int t = threadIdx.x;
    int c = t & 63;
    int rg = t >> 6;
    int base = blockIdx.x * 1024;
    float sc = scale[c], sh = shift[c];
    int gcur = -1;
    float acc = 0.f, cacc = 0.f;
    for (int i = rg; i < 1024; i += 4) {
        int v = base + i;
        if (v >= N_NODES) break;
        int g = batch[v];
        if (g != gcur) {
            if (gcur >= 0) {
                atomicAdd(&pooled[gcur * 64 + c], acc);
                if (c == 0) atomicAdd(&pcnt[gcur], cacc);
            }
            gcur = g;
            acc = 0.f;
            cacc = 0.f;
        }
        float h = fmaxf(sc * (float)a2[(size_t)v * 64 + c] + sh, 0.f);
        acc += h;
        cacc += 1.f;
    }
    if (gcur >= 0) {
        atomicAdd(&pooled[gcur * 64 + c], acc);
        if (c == 0) atomicAdd(&pcnt[gcur], cacc);
    }
}

__global__ void k_out(const float* __restrict__ pooled, const float* __restrict__ pcnt,
                      const float* __restrict__ Wout, const float* __restrict__ bout,
                      float* __restrict__ out) {
    int g = threadIdx.x;
    if (g < N_GRAPHS) {
        float cnt = fmaxf(pcnt[g], 1.0f);
        float s = 0.f;
        for (int c = 0; c < 64; ++c) s += pooled[g * 64 + c] * Wout[c];
        out[g] = s / cnt + bout[0];
    }
}

// ---------------------------------------------------------------------------
extern "C" void kernel_launch(void* const* d_in, const int* in_sizes, int n_in,
                              void* d_out, int out_size, void* d_ws, size_t ws_size,
                              hipStream_t stream) {
    const float* x    = (const float*)d_in[0];
    const int*   ei   = (const int*)d_in[1];
    const float* ew   = (const float*)d_in[2];
    const int*   batch= (const int*)d_in[3];
    const float* W1   = (const float*)d_in[4];
    const float* b1   = (const float*)d_in[5];
    const float* W2   = (const float*)d_in[6];
    const float* b2   = (const float*)d_in[7];
    const float* g1   = (const float*)d_in[8];
    const float* be1  = (const float*)d_in[9];
    const float* g2   = (const float*)d_in[10];
    const float* be2  = (const float*)d_in[11];
    const float* Wout = (const float*)d_in[12];
    const float* bout = (const float*)d_in[13];
    float* out = (float*)d_out;

    char* w = (char*)d_ws;
    size_t o = 0;
    auto alloc = [&](size_t bytes) -> void* {
        void* p = w + o;
        o = (o + bytes + 255) & ~(size_t)255;
        return p;
    };
    int*   cnt2    = (int*)alloc(NCNT * 4);
    int*   soff    = (int*)alloc((NCNT + 1) * 4);
    int*   cur     = (int*)alloc(NCNT * 4);
    int*   nptr    = (int*)alloc((N_NODES + 1) * 4);
    float* dinv    = (float*)alloc(N_NODES * 4);
    float* bnshard = (float*)alloc(NSHARD * 128 * 4);
    float* scale1  = (float*)alloc(64 * 4);
    float* shift1  = (float*)alloc(64 * 4);
    float* scale2  = (float*)alloc(64 * 4);
    float* shift2  = (float*)alloc(64 * 4);
    float* pooled  = (float*)alloc(N_GRAPHS * 64 * 4);
    float* pcnt    = (float*)alloc(N_GRAPHS * 4);
    uint2* ebuf2   = (uint2*)alloc((size_t)N_EDGES * 8);
    // 25.6 MB region triple-use: ebuf (binning scratch, dead after k_sortnorm)
    // then two fp16 node buffers HA/HB (12.8 MB each), written only after.
    uint2* ebuf    = (uint2*)alloc((size_t)N_EDGES * 8);
    _Float16* bufHA = (_Float16*)ebuf;
    _Float16* bufHB = bufHA + (size_t)N_NODES * 64;
    if (o > ws_size) return;

    (void)hipMemsetAsync(cnt2, 0, NCNT * 4, stream);
    (void)hipMemsetAsync(bnshard, 0, NSHARD * 128 * 4, stream);
    (void)hipMemsetAsync(pooled, 0, N_GRAPHS * 64 * 4, stream);
    (void)hipMemsetAsync(pcnt, 0, N_GRAPHS * 4, stream);

    k_count<<<BIN_BLOCKS, 256, 0, stream>>>(ei, cnt2);
    k_scan6k<<<1, 256, 0, stream>>>(cnt2, soff, cur, nptr);
    k_bin<<<BIN_BLOCKS, 256, 0, stream>>>(ei, ew, cur, ebuf);
    k_degb<<<NBUCK, 256, 0, stream>>>(ebuf, soff, dinv);
    k_sortnorm<<<NBUCK, 256, 0, stream>>>(ebuf, soff, dinv, ebuf2, nptr);

    // layer 1: x (f32) -> h1 (fp16) -> a1 (fp16) + BN1 stats
    k_gemm<128, false><<<(N_NODES + 127) / 128, 256, 0, stream>>>(x, W1, nullptr, nullptr, bufHA);
    k_agg<<<N_NODES / 32, 256, 0, stream>>>(bufHA, ebuf2, nptr, dinv, b1, bufHB, bnshard);
    k_bn_final<<<1, 256, 0, stream>>>(bnshard, g1, be1, scale1, shift1);

    // layer 2: a1 (fp16, fused BN+ReLU) -> h2 (fp16) -> a2 (fp16) + BN2 stats
    k_gemm<64, true><<<(N_NODES + 127) / 128, 256, 0, stream>>>(bufHB, W2, scale1, shift1, bufHA);
    k_agg<<<N_NODES / 32, 256, 0, stream>>>(bufHA, ebuf2, nptr, dinv, b2, bufHB, bnshard);
    k_bn_final<<<1, 256, 0, stream>>>(bnshard, g2, be2, scale2, shift2);

    // pool (fused BN2+ReLU) + output
    k_pool<<<(N_NODES + 1023) / 1024, 256, 0, stream>>>(bufHB, scale2, shift2, batch, pooled, pcnt);
    k_out<<<1, 64, 0, stream>>>(pooled, pcnt, Wout, bout, out);
}

// Round 11
// 442.050 us; speedup vs baseline: 2.3863x; 1.2003x over previous
//
#include <hip/hip_runtime.h>
#include <stdint.h>

#define N_NODES 100000
#define N_EDGES 3200000
#define IN_DIM 128
#define HID 64
#define N_GRAPHS 64
#define BN_EPS 1e-5f
#define NSHARD 16
#define BUCK_SH 7
#define BUCK_SZ 128
#define NBUCK ((N_NODES + BUCK_SZ - 1) / BUCK_SZ)   // 782
#define NCNT (NBUCK * 8)                             // 6256
#define BINB_EDGES 4096                              // edges per binning block
#define BIN_BLOCKS ((N_EDGES + BINB_EDGES - 1) / BINB_EDGES)  // 782
#define EDGE_CAP 6016                                // LDS edge stage (mean 4092)
#define AGG_CAP 2048                                 // agg block edge stage (mean 1024)

// __builtin_nontemporal_load needs native (ext_vector) types, not HIP structs.
typedef float vf4 __attribute__((ext_vector_type(4)));
typedef int   vi4 __attribute__((ext_vector_type(4)));
typedef unsigned vu2 __attribute__((ext_vector_type(2)));
typedef _Float16 vh4 __attribute__((ext_vector_type(4)));

__device__ __forceinline__ float4 nt_f4(const float* p) {
    vf4 v = __builtin_nontemporal_load((const vf4*)p);
    return make_float4(v.x, v.y, v.z, v.w);
}
__device__ __forceinline__ int4 nt_i4(const int* p) {
    vi4 v = __builtin_nontemporal_load((const vi4*)p);
    return make_int4(v.x, v.y, v.z, v.w);
}
__device__ __forceinline__ uint2 nt_u2(const uint2* p) {
    vu2 v = __builtin_nontemporal_load((const vu2*)p);
    return make_uint2(v.x, v.y);
}
__device__ __forceinline__ vh4 nt_h4(const _Float16* p) {
    return __builtin_nontemporal_load((const vh4*)p);
}

// ---------------------------------------------------------------------------
// block-aggregated count: LDS histogram per block (4096 edges), then ONE
// global atomic per non-empty (bucket, s). s = blockIdx&7 = XCD id.
__global__ __launch_bounds__(256) void k_count(const int* __restrict__ ei,
                                               int* __restrict__ cnt2) {
    __shared__ int hist[NBUCK];
    int b = blockIdx.x, t = threadIdx.x;
    int s = b & 7;
    int base = b * BINB_EDGES;
    int n = min(BINB_EDGES, N_EDGES - base);
    for (int i = t; i < NBUCK; i += 256) hist[i] = 0;
    __syncthreads();
#pragma unroll
    for (int k = 0; k < 4; ++k) {
        int ch = t + 256 * k;
        if (4 * ch < n) {
            int4 c4 = nt_i4(ei + N_EDGES + base + 4 * ch);
            atomicAdd(&hist[c4.x >> BUCK_SH], 1);
            atomicAdd(&hist[c4.y >> BUCK_SH], 1);
            atomicAdd(&hist[c4.z >> BUCK_SH], 1);
            atomicAdd(&hist[c4.w >> BUCK_SH], 1);
        }
    }
    __syncthreads();
    for (int j = t; j < NBUCK; j += 256) {
        int h = hist[j];
        if (h > 0) atomicAdd(&cnt2[(j << 3) + s], h);
    }
}

// single-block exclusive scan of cnt2[6256] -> soff[6257]; init cursors; nptr tail
__global__ void k_scan6k(const int* __restrict__ cnt2, int* __restrict__ soff,
                         int* __restrict__ cur, int* __restrict__ nptr) {
    __shared__ int parts[256];
    int t = threadIdx.x;
    int s = 0;
    for (int i = 0; i < 25; ++i) {
        int idx = t * 25 + i;
        if (idx < NCNT) s += cnt2[idx];
    }
    parts[t] = s;
    __syncthreads();
    for (int off = 1; off < 256; off <<= 1) {
        int x = (t >= off) ? parts[t - off] : 0;
        __syncthreads();
        parts[t] += x;
        __syncthreads();
    }
    int run = (t > 0) ? parts[t - 1] : 0;
    for (int i = 0; i < 25; ++i) {
        int idx = t * 25 + i;
        if (idx < NCNT) {
            soff[idx] = run;
            cur[idx] = run;
            run += cnt2[idx];
        }
    }
    if (t == 255) soff[NCNT] = parts[255];
    if (t == 0) nptr[N_NODES] = N_EDGES;
}

// block-aggregated bin: stage 4096 edges in LDS, histogram, reserve one global
// range per non-empty bucket, scatter from LDS (round-8 structure, proven).
__global__ __launch_bounds__(256) void k_bin(const int* __restrict__ ei,
                                             const float* __restrict__ ew,
                                             int* __restrict__ cur,
                                             uint2* __restrict__ ebuf) {
    __shared__ uint2 sed[BINB_EDGES];
    __shared__ unsigned short sbk[BINB_EDGES];
    __shared__ int hist[NBUCK];
    int b = blockIdx.x, t = threadIdx.x;
    int s = b & 7;
    int base = b * BINB_EDGES;
    int n = min(BINB_EDGES, N_EDGES - base);
    for (int i = t; i < NBUCK; i += 256) hist[i] = 0;
    __syncthreads();
#pragma unroll
    for (int k = 0; k < 4; ++k) {
        int ch = t + 256 * k;
        if (4 * ch < n) {
            int4 r4 = nt_i4(ei + base + 4 * ch);
            int4 c4 = nt_i4(ei + N_EDGES + base + 4 * ch);
            float4 w4 = nt_f4(ew + base + 4 * ch);
            int rr[4] = {r4.x, r4.y, r4.z, r4.w};
            int cc[4] = {c4.x, c4.y, c4.z, c4.w};
            float ww[4] = {w4.x, w4.y, w4.z, w4.w};
#pragma unroll
            for (int u = 0; u < 4; ++u) {
                int li = 4 * ch + u;
                sed[li] = make_uint2(
                    (unsigned)(rr[u] | ((cc[u] & (BUCK_SZ - 1)) << 17)),
                    __float_as_uint(ww[u]));
                int bk = cc[u] >> BUCK_SH;
                sbk[li] = (unsigned short)bk;
                atomicAdd(&hist[bk], 1);
            }
        }
    }
    __syncthreads();
    for (int j = t; j < NBUCK; j += 256) {
        int h = hist[j];
        if (h > 0) hist[j] = atomicAdd(&cur[(j << 3) + s], h);
    }
    __syncthreads();
    for (int i = t; i < n; i += 256) {
        int bk = sbk[i];
        int pos = atomicAdd(&hist[bk], 1);
        ebuf[pos] = sed[i];
    }
}

// per-bucket weighted degree -> dinv (bucket-local edges, LDS atomics only)
__global__ __launch_bounds__(256) void k_degb(const uint2* __restrict__ ebuf,
                                              const int* __restrict__ soff,
                                              float* __restrict__ dinv) {
    __shared__ float dacc[BUCK_SZ];
    int b = blockIdx.x, t = threadIdx.x;
    if (t < BUCK_SZ) dacc[t] = 0.f;
    __syncthreads();
    int beg = soff[b << 3], end = soff[(b << 3) + 8];
    for (int i = beg + t; i < end; i += 256) {
        uint2 u = nt_u2(ebuf + i);
        atomicAdd(&dacc[u.x >> 17], __uint_as_float(u.y));
    }
    __syncthreads();
    int node = b * BUCK_SZ + t;
    if (t < BUCK_SZ && node < N_NODES) dinv[node] = rsqrtf(dacc[t] + 1.0f);
}

// per-bucket counting sort by local dest + norm (dinv complete before launch)
__global__ __launch_bounds__(256) void k_sortnorm(const uint2* __restrict__ ebuf,
                                                  const int* __restrict__ soff,
                                                  const float* __restrict__ dinv,
                                                  uint2* __restrict__ ebuf2,
                                                  int* __restrict__ nptr) {
    __shared__ uint2 se[EDGE_CAP];
    __shared__ float sdi[BUCK_SZ];
    __shared__ int scnt[BUCK_SZ];
    __shared__ int scur[BUCK_SZ];
    int b = blockIdx.x, t = threadIdx.x;
    if (t < BUCK_SZ) {
        scnt[t] = 0;
        int node = b * BUCK_SZ + t;
        sdi[t] = (node < N_NODES) ? dinv[node] : 0.f;
    }
    __syncthreads();
    int beg = soff[b << 3], end = soff[(b << 3) + 8];
    int n = end - beg;
    bool fit = (n <= EDGE_CAP);
    for (int i = t; i < n; i += 256) {
        uint2 u = nt_u2(ebuf + beg + i);
        if (fit) se[i] = u;
        atomicAdd(&scnt[u.x >> 17], 1);
    }
    __syncthreads();
    for (int off = 1; off < BUCK_SZ; off <<= 1) {
        int x = 0;
        if (t < BUCK_SZ && t >= off) x = scnt[t - off];
        __syncthreads();
        if (t < BUCK_SZ) scnt[t] += x;
        __syncthreads();
    }
    if (t < BUCK_SZ) {
        int excl = (t > 0) ? scnt[t - 1] : 0;
        scur[t] = beg + excl;
        int node = b * BUCK_SZ + t;
        if (node < N_NODES) nptr[node] = beg + excl;
    }
    __syncthreads();
    for (int i = t; i < n; i += 256) {
        uint2 u = fit ? se[i] : nt_u2(ebuf + beg + i);
        int r = u.x & 131071;
        int cl = u.x >> 17;
        float nm = dinv[r] * __uint_as_float(u.y) * sdi[cl];
        int p = atomicAdd(&scur[cl], 1);
        ebuf2[p] = make_uint2((unsigned)r, __float_as_uint(nm));
    }
}

// ---------------------------------------------------------------------------
// GEMM: out[n][c] = sum_k in[n][k]*W[k][c]; fp16 output.
// BNH: input is fp16 with fused BN+ReLU (layer 2); else f32 input (layer 1).
template <int K, bool BNH>
__global__ __launch_bounds__(256) void k_gemm(const void* __restrict__ in_,
                                              const float* __restrict__ W,
                                              const float* __restrict__ scale,
                                              const float* __restrict__ shift,
                                              _Float16* __restrict__ out) {
    __shared__ float ws[K * 64];
    __shared__ float xs[32 * 132];
    __shared__ float ssc[64], ssh[64];
    int t = threadIdx.x;
    int nbase = blockIdx.x * 128;

#pragma unroll
    for (int i = 0; i < K / 16; ++i) {
        int idx = t + 256 * i;
        ((float4*)ws)[idx] = ((const float4*)W)[idx];
    }
    if (BNH && t < 64) { ssc[t] = scale[t]; ssh[t] = shift[t]; }

    int cg = t & 15;
    int ng = t >> 4;
    float acc[8][4];
#pragma unroll
    for (int i = 0; i < 8; ++i)
#pragma unroll
        for (int j = 0; j < 4; ++j) acc[i][j] = 0.f;

    for (int k0 = 0; k0 < K; k0 += 32) {
        __syncthreads();
#pragma unroll
        for (int i = 0; i < 4; ++i) {
            int idx = t + 256 * i;
            int row = idx >> 3;
            int kq = idx & 7;
            int node = nbase + row;
            float vv[4] = {0.f, 0.f, 0.f, 0.f};
            if (node < N_NODES) {
                if (BNH) {
                    vh4 v = nt_h4((const _Float16*)in_ + (size_t)node * K + k0 + kq * 4);
                    vv[0] = (float)v.x; vv[1] = (float)v.y;
                    vv[2] = (float)v.z; vv[3] = (float)v.w;
                } else {
                    float4 v = nt_f4((const float*)in_ + (size_t)node * K + k0 + kq * 4);
                    vv[0] = v.x; vv[1] = v.y; vv[2] = v.z; vv[3] = v.w;
                }
            }
#pragma unroll
            for (int u = 0; u < 4; ++u) {
                float val = vv[u];
                if (BNH) {
                    int k = k0 + kq * 4 + u;
                    val = fmaxf(ssc[k] * val + ssh[k], 0.f);
                }
                xs[(kq * 4 + u) * 132 + row] = val;
            }
        }
        __syncthreads();
#pragma unroll
        for (int k = 0; k < 32; ++k) {
            float4 wv = *(const float4*)(ws + (k0 + k) * 64 + cg * 4);
            float4 xa = *(const float4*)(xs + k * 132 + ng * 8);
            float4 xb = *(const float4*)(xs + k * 132 + ng * 8 + 4);
            float xv[8] = {xa.x, xa.y, xa.z, xa.w, xb.x, xb.y, xb.z, xb.w};
            float wvv[4] = {wv.x, wv.y, wv.z, wv.w};
#pragma unroll
            for (int i = 0; i < 8; ++i)
#pragma unroll
                for (int j = 0; j < 4; ++j) acc[i][j] += xv[i] * wvv[j];
        }
    }
#pragma unroll
    for (int i = 0; i < 8; ++i) {
        int node = nbase + ng * 8 + i;
        if (node < N_NODES) {
            vh4 o;
            o.x = (_Float16)acc[i][0]; o.y = (_Float16)acc[i][1];
            o.z = (_Float16)acc[i][2]; o.w = (_Float16)acc[i][3];
            *(vh4*)(out + (size_t)node * 64 + cg * 4) = o;
        }
    }
}

// ---------------------------------------------------------------------------
// CSR gather-aggregation v3: block stages its 32 nodes' contiguous edge metas
// in LDS (one coalesced pass), so the per-edge path is ds_read -> row gather
// with no VMEM->VMEM dependency chain; row gathers pile up many-deep.
__global__ __launch_bounds__(256) void k_agg(const _Float16* __restrict__ hin,
                                             const uint2* __restrict__ ebuf2,
                                             const int* __restrict__ nptr,
                                             const float* __restrict__ dinv,
                                             const float* __restrict__ bias,
                                             _Float16* __restrict__ hout,
                                             float* __restrict__ bn_shard) {
    __shared__ uint2 sme[AGG_CAP];
    __shared__ float sm[4][64], qm[4][64];
    int b = blockIdx.x, t = threadIdx.x;
    int wave = t >> 6, lane = t & 63;
    int vbase0 = b * 32;                       // grid is exactly N_NODES/32
    int ebeg = nptr[vbase0];
    int eend = nptr[vbase0 + 32];
    int n = eend - ebeg;
    bool fit = (n <= AGG_CAP);
    if (fit) {
        for (int i = t; i < n; i += 256) sme[i] = nt_u2(ebuf2 + ebeg + i);
    }
    __syncthreads();

    float s = 0.f, q = 0.f;
    float bl = bias[lane];
    int vbase = vbase0 + wave * 8;
    for (int vi = 0; vi < 8; ++vi) {
        int v = vbase + vi;
        int beg = nptr[v], end = nptr[v + 1];
        float acc = 0.f;
        int j = beg;
        if (fit) {
            for (; j + 8 <= end; j += 8) {
                float fv[8], fn[8];
#pragma unroll
                for (int u = 0; u < 8; ++u) {
                    uint2 e = sme[j - ebeg + u];
                    fn[u] = __uint_as_float(e.y);
                    fv[u] = (float)hin[((size_t)e.x << 6) + lane];
                }
#pragma unroll
                for (int u = 0; u < 8; ++u) acc = fmaf(fn[u], fv[u], acc);
            }
            for (; j < end; ++j) {
                uint2 e = sme[j - ebeg];
                acc = fmaf(__uint_as_float(e.y),
                           (float)hin[((size_t)e.x << 6) + lane], acc);
            }
        } else {
            for (; j + 8 <= end; j += 8) {
                float fv[8], fn[8];
#pragma unroll
                for (int u = 0; u < 8; ++u) {
                    uint2 e = nt_u2(ebuf2 + j + u);
                    fn[u] = __uint_as_float(e.y);
                    fv[u] = (float)hin[((size_t)e.x << 6) + lane];
                }
#pragma unroll
                for (int u = 0; u < 8; ++u) acc = fmaf(fn[u], fv[u], acc);
            }
            for (; j < end; ++j) {
                uint2 e = nt_u2(ebuf2 + j);
                acc = fmaf(__uint_as_float(e.y),
                           (float)hin[((size_t)e.x << 6) + lane], acc);
            }
        }
        float dv = dinv[v];
        acc = fmaf(dv * dv, (float)hin[((size_t)v << 6) + lane], acc);
        acc += bl;
        hout[((size_t)v << 6) + lane] = (_Float16)acc;
        s += acc;
        q += acc * acc;
    }
    sm[wave][lane] = s;
    qm[wave][lane] = q;
    __syncthreads();
    if (wave == 0) {
        float ts = sm[0][lane] + sm[1][lane] + sm[2][lane] + sm[3][lane];
        float tq = qm[0][lane] + qm[1][lane] + qm[2][lane] + qm[3][lane];
        float* shard = bn_shard + (blockIdx.x & (NSHARD - 1)) * 128;
        atomicAdd(&shard[lane], ts);
        atomicAdd(&shard[64 + lane], tq);
    }
}

// reduce BN shards -> scale/shift; re-zero shards for the next layer
__global__ void k_bn_final(float* __restrict__ bn_shard, const float* __restrict__ gamma,
                           const float* __restrict__ beta, float* __restrict__ scale,
                           float* __restrict__ shift) {
    int t = threadIdx.x;
    if (t < 64) {
        float s = 0.f, q = 0.f;
        for (int i = 0; i < NSHARD; ++i) {
            s += bn_shard[i * 128 + t];
            q += bn_shard[i * 128 + 64 + t];
        }
        float mean = s * (1.0f / N_NODES);
        float var = q * (1.0f / N_NODES) - mean * mean;
        float sc = gamma[t] * rsqrtf(var + BN_EPS);
        scale[t] = sc;
        shift[t] = beta[t] - mean * sc;
    }
    __syncthreads();
    for (int i = t; i < NSHARD * 128; i += 256) bn_shard[i] = 0.f;
}

// ---------------------------------------------------------------------------
// pool v2: 782 blocks x 128 rows (8x parallelism vs the 98-block version that
// profiled at 3.5% occupancy / 130 us). Sharded accumulators (blockIdx&15,
// XCD-local) bound the atomic contention; k_out reduces the shards.
__global__ __launch_bounds__(256) void k_pool(const _Float16* __restrict__ a2,
                                              const float* __restrict__ scale,
                                              const float* __restrict__ shift,
                                              const int* __restrict__ batch,
                                              float* __restrict__ pooled_sh,
                                              float* __restrict__ pcnt_sh) {
    int b = blockIdx.x, t = threadIdx.x;
    int c = t & 63;
    int rg = t >> 6;
    int base = b * BUCK_SZ;
    float sc = scale[c], sh = shift[c];
    float* pool_s = pooled_sh + (size_t)(b & (NSHARD - 1)) * (N_GRAPHS * 64);
    float* pcnt_s = pcnt_sh + (size_t)(b & (NSHARD - 1)) * N_GRAPHS;
    int gcur = -1;
    float acc = 0.f, cacc = 0.f;
    for (int i = rg; i < BUCK_SZ; i += 4) {
        int v = base + i;
        if (v >= N_NODES) break;
        int g = batch[v];
        if (g != gcur) {
            if (gcur >= 0) {
                atomicAdd(&pool_s[gcur * 64 + c], acc);
                if (c == 0) atomicAdd(&pcnt_s[gcur], cacc);
            }
            gcur = g;
            acc = 0.f;
            cacc = 0.f;
        }
        float h = fmaxf(sc * (float)a2[(size_t)v * 64 + c] + sh, 0.f);
        acc += h;
        cacc += 1.f;
    }
    if (gcur >= 0) {
        atomicAdd(&pool_s[gcur * 64 + c], acc);
        if (c == 0) atomicAdd(&pcnt_s[gcur], cacc);
    }
}

__global__ void k_out(const float* __restrict__ pooled_sh,
                      const float* __restrict__ pcnt_sh,
                      const float* __restrict__ Wout, const float* __restrict__ bout,
                      float* __restrict__ out) {
    int g = threadIdx.x;
    if (g < N_GRAPHS) {
        float cnt = 0.f;
        for (int s = 0; s < NSHARD; ++s) cnt += pcnt_sh[s * N_GRAPHS + g];
        cnt = fmaxf(cnt, 1.0f);
        float sum = 0.f;
        for (int c = 0; c < 64; ++c) {
            float p = 0.f;
            for (int s = 0; s < NSHARD; ++s)
                p += pooled_sh[(size_t)s * N_GRAPHS * 64 + g * 64 + c];
            sum += p * Wout[c];
        }
        out[g] = sum / cnt + bout[0];
    }
}

// ---------------------------------------------------------------------------
extern "C" void kernel_launch(void* const* d_in, const int* in_sizes, int n_in,
                              void* d_out, int out_size, void* d_ws, size_t ws_size,
                              hipStream_t stream) {
    const float* x    = (const float*)d_in[0];
    const int*   ei   = (const int*)d_in[1];
    const float* ew   = (const float*)d_in[2];
    const int*   batch= (const int*)d_in[3];
    const float* W1   = (const float*)d_in[4];
    const float* b1   = (const float*)d_in[5];
    const float* W2   = (const float*)d_in[6];
    const float* b2   = (const float*)d_in[7];
    const float* g1   = (const float*)d_in[8];
    const float* be1  = (const float*)d_in[9];
    const float* g2   = (const float*)d_in[10];
    const float* be2  = (const float*)d_in[11];
    const float* Wout = (const float*)d_in[12];
    const float* bout = (const float*)d_in[13];
    float* out = (float*)d_out;

    char* w = (char*)d_ws;
    size_t o = 0;
    auto alloc = [&](size_t bytes) -> void* {
        void* p = w + o;
        o = (o + bytes + 255) & ~(size_t)255;
        return p;
    };
    int*   cnt2    = (int*)alloc(NCNT * 4);
    int*   soff    = (int*)alloc((NCNT + 1) * 4);
    int*   cur     = (int*)alloc(NCNT * 4);
    int*   nptr    = (int*)alloc((N_NODES + 1) * 4);
    float* dinv    = (float*)alloc(N_NODES * 4);
    float* bnshard = (float*)alloc(NSHARD * 128 * 4);
    float* scale1  = (float*)alloc(64 * 4);
    float* shift1  = (float*)alloc(64 * 4);
    float* scale2  = (float*)alloc(64 * 4);
    float* shift2  = (float*)alloc(64 * 4);
    float* pooled  = (float*)alloc(NSHARD * N_GRAPHS * 64 * 4);
    float* pcnt    = (float*)alloc(NSHARD * N_GRAPHS * 4);
    uint2* ebuf2   = (uint2*)alloc((size_t)N_EDGES * 8);
    // 25.6 MB region triple-use: ebuf (binning scratch, dead after k_sortnorm)
    // then two fp16 node buffers HA/HB (12.8 MB each), written only after.
    uint2* ebuf    = (uint2*)alloc((size_t)N_EDGES * 8);
    _Float16* bufHA = (_Float16*)ebuf;
    _Float16* bufHB = bufHA + (size_t)N_NODES * 64;
    if (o > ws_size) return;

    (void)hipMemsetAsync(cnt2, 0, NCNT * 4, stream);
    (void)hipMemsetAsync(bnshard, 0, NSHARD * 128 * 4, stream);
    (void)hipMemsetAsync(pooled, 0, NSHARD * N_GRAPHS * 64 * 4, stream);
    (void)hipMemsetAsync(pcnt, 0, NSHARD * N_GRAPHS * 4, stream);

    k_count<<<BIN_BLOCKS, 256, 0, stream>>>(ei, cnt2);
    k_scan6k<<<1, 256, 0, stream>>>(cnt2, soff, cur, nptr);
    k_bin<<<BIN_BLOCKS, 256, 0, stream>>>(ei, ew, cur, ebuf);
    k_degb<<<NBUCK, 256, 0, stream>>>(ebuf, soff, dinv);
    k_sortnorm<<<NBUCK, 256, 0, stream>>>(ebuf, soff, dinv, ebuf2, nptr);

    // layer 1: x (f32) -> h1 (fp16) -> a1 (fp16) + BN1 stats
    k_gemm<128, false><<<(N_NODES + 127) / 128, 256, 0, stream>>>(x, W1, nullptr, nullptr, bufHA);
    k_agg<<<N_NODES / 32, 256, 0, stream>>>(bufHA, ebuf2, nptr, dinv, b1, bufHB, bnshard);
    k_bn_final<<<1, 256, 0, stream>>>(bnshard, g1, be1, scale1, shift1);

    // layer 2: a1 (fp16, fused BN+ReLU) -> h2 (fp16) -> a2 (fp16) + BN2 stats
    k_gemm<64, true><<<(N_NODES + 127) / 128, 256, 0, stream>>>(bufHB, W2, scale1, shift1, bufHA);
    k_agg<<<N_NODES / 32, 256, 0, stream>>>(bufHA, ebuf2, nptr, dinv, b2, bufHB, bnshard);
    k_bn_final<<<1, 256, 0, stream>>>(bnshard, g2, be2, scale2, shift2);

    // pool (fused BN2+ReLU, sharded accumulators) + output
    k_pool<<<NBUCK, 256, 0, stream>>>(bufHB, scale2, shift2, batch, pooled, pcnt);
    k_out<<<1, 64, 0, stream>>>(pooled, pcnt, Wout, bout, out);
}

// Round 12
// 427.727 us; speedup vs baseline: 2.4662x; 1.0335x over previous
//
#include <hip/hip_runtime.h>
#include <stdint.h>

#define N_NODES 100000
#define N_EDGES 3200000
#define IN_DIM 128
#define HID 64
#define N_GRAPHS 64
#define BN_EPS 1e-5f
#define NSHARD 16
#define BUCK_SH 7
#define BUCK_SZ 128
#define NBUCK ((N_NODES + BUCK_SZ - 1) / BUCK_SZ)   // 782
#define NCNT (NBUCK * 8)                             // 6256
#define BINB_EDGES 4096                              // edges per binning block
#define BIN_BLOCKS ((N_EDGES + BINB_EDGES - 1) / BINB_EDGES)  // 782
#define EDGE_CAP 6016                                // LDS edge stage (mean 4092)
#define AGG_CAP 2048                                 // agg block edge stage (mean 1024)

// __builtin_nontemporal_load needs native (ext_vector) types, not HIP structs.
typedef float vf4 __attribute__((ext_vector_type(4)));
typedef int   vi4 __attribute__((ext_vector_type(4)));
typedef unsigned vu2 __attribute__((ext_vector_type(2)));
typedef _Float16 vh4 __attribute__((ext_vector_type(4)));

__device__ __forceinline__ float4 nt_f4(const float* p) {
    vf4 v = __builtin_nontemporal_load((const vf4*)p);
    return make_float4(v.x, v.y, v.z, v.w);
}
__device__ __forceinline__ int4 nt_i4(const int* p) {
    vi4 v = __builtin_nontemporal_load((const vi4*)p);
    return make_int4(v.x, v.y, v.z, v.w);
}
__device__ __forceinline__ uint2 nt_u2(const uint2* p) {
    vu2 v = __builtin_nontemporal_load((const vu2*)p);
    return make_uint2(v.x, v.y);
}
__device__ __forceinline__ vh4 nt_h4(const _Float16* p) {
    return __builtin_nontemporal_load((const vh4*)p);
}

// ---------------------------------------------------------------------------
// block-aggregated count: LDS histogram per block (4096 edges), then ONE
// global atomic per non-empty (bucket, s). s = blockIdx&7 = XCD id.
__global__ __launch_bounds__(256) void k_count(const int* __restrict__ ei,
                                               int* __restrict__ cnt2) {
    __shared__ int hist[NBUCK];
    int b = blockIdx.x, t = threadIdx.x;
    int s = b & 7;
    int base = b * BINB_EDGES;
    int n = min(BINB_EDGES, N_EDGES - base);
    for (int i = t; i < NBUCK; i += 256) hist[i] = 0;
    __syncthreads();
#pragma unroll
    for (int k = 0; k < 4; ++k) {
        int ch = t + 256 * k;
        if (4 * ch < n) {
            int4 c4 = nt_i4(ei + N_EDGES + base + 4 * ch);
            atomicAdd(&hist[c4.x >> BUCK_SH], 1);
            atomicAdd(&hist[c4.y >> BUCK_SH], 1);
            atomicAdd(&hist[c4.z >> BUCK_SH], 1);
            atomicAdd(&hist[c4.w >> BUCK_SH], 1);
        }
    }
    __syncthreads();
    for (int j = t; j < NBUCK; j += 256) {
        int h = hist[j];
        if (h > 0) atomicAdd(&cnt2[(j << 3) + s], h);
    }
}

// single-block exclusive scan of cnt2[6256] -> soff[6257]; init cursors; nptr tail
__global__ void k_scan6k(const int* __restrict__ cnt2, int* __restrict__ soff,
                         int* __restrict__ cur, int* __restrict__ nptr) {
    __shared__ int parts[256];
    int t = threadIdx.x;
    int s = 0;
    for (int i = 0; i < 25; ++i) {
        int idx = t * 25 + i;
        if (idx < NCNT) s += cnt2[idx];
    }
    parts[t] = s;
    __syncthreads();
    for (int off = 1; off < 256; off <<= 1) {
        int x = (t >= off) ? parts[t - off] : 0;
        __syncthreads();
        parts[t] += x;
        __syncthreads();
    }
    int run = (t > 0) ? parts[t - 1] : 0;
    for (int i = 0; i < 25; ++i) {
        int idx = t * 25 + i;
        if (idx < NCNT) {
            soff[idx] = run;
            cur[idx] = run;
            run += cnt2[idx];
        }
    }
    if (t == 255) soff[NCNT] = parts[255];
    if (t == 0) nptr[N_NODES] = N_EDGES;
}

// block-aggregated bin: stage 4096 edges in LDS, histogram, reserve one global
// range per non-empty bucket, scatter from LDS (round-8 structure, proven).
__global__ __launch_bounds__(256) void k_bin(const int* __restrict__ ei,
                                             const float* __restrict__ ew,
                                             int* __restrict__ cur,
                                             uint2* __restrict__ ebuf) {
    __shared__ uint2 sed[BINB_EDGES];
    __shared__ unsigned short sbk[BINB_EDGES];
    __shared__ int hist[NBUCK];
    int b = blockIdx.x, t = threadIdx.x;
    int s = b & 7;
    int base = b * BINB_EDGES;
    int n = min(BINB_EDGES, N_EDGES - base);
    for (int i = t; i < NBUCK; i += 256) hist[i] = 0;
    __syncthreads();
#pragma unroll
    for (int k = 0; k < 4; ++k) {
        int ch = t + 256 * k;
        if (4 * ch < n) {
            int4 r4 = nt_i4(ei + base + 4 * ch);
            int4 c4 = nt_i4(ei + N_EDGES + base + 4 * ch);
            float4 w4 = nt_f4(ew + base + 4 * ch);
            int rr[4] = {r4.x, r4.y, r4.z, r4.w};
            int cc[4] = {c4.x, c4.y, c4.z, c4.w};
            float ww[4] = {w4.x, w4.y, w4.z, w4.w};
#pragma unroll
            for (int u = 0; u < 4; ++u) {
                int li = 4 * ch + u;
                sed[li] = make_uint2(
                    (unsigned)(rr[u] | ((cc[u] & (BUCK_SZ - 1)) << 17)),
                    __float_as_uint(ww[u]));
                int bk = cc[u] >> BUCK_SH;
                sbk[li] = (unsigned short)bk;
                atomicAdd(&hist[bk], 1);
            }
        }
    }
    __syncthreads();
    for (int j = t; j < NBUCK; j += 256) {
        int h = hist[j];
        if (h > 0) hist[j] = atomicAdd(&cur[(j << 3) + s], h);
    }
    __syncthreads();
    for (int i = t; i < n; i += 256) {
        int bk = sbk[i];
        int pos = atomicAdd(&hist[bk], 1);
        ebuf[pos] = sed[i];
    }
}

// ---------------------------------------------------------------------------
// fused prep (dinv-factorized): per bucket, ONE ebuf read pass computes
// weighted degree -> dinv[c] (bucket-LOCAL, no remote reads -> no round-5
// race), dest histogram -> per-node CSR offsets, then scatters edges with
// w' = w * dinv[c]. dinv[r] is folded into node features by the GEMM
// epilogue instead, so it is never needed here.
__global__ __launch_bounds__(256) void k_sortnorm(const uint2* __restrict__ ebuf,
                                                  const int* __restrict__ soff,
                                                  float* __restrict__ dinv,
                                                  uint2* __restrict__ ebuf2,
                                                  int* __restrict__ nptr) {
    __shared__ uint2 se[EDGE_CAP];
    __shared__ float sdi[BUCK_SZ];   // degree accum, then dinv
    __shared__ int scnt[BUCK_SZ];
    __shared__ int scur[BUCK_SZ];
    int b = blockIdx.x, t = threadIdx.x;
    if (t < BUCK_SZ) { sdi[t] = 0.f; scnt[t] = 0; }
    __syncthreads();
    int beg = soff[b << 3], end = soff[(b << 3) + 8];
    int n = end - beg;
    bool fit = (n <= EDGE_CAP);
    // pass 1: stage edges + weighted degree + dest histogram
    for (int i = t; i < n; i += 256) {
        uint2 u = nt_u2(ebuf + beg + i);
        if (fit) se[i] = u;
        int cl = u.x >> 17;
        atomicAdd(&sdi[cl], __uint_as_float(u.y));
        atomicAdd(&scnt[cl], 1);
    }
    __syncthreads();
    if (t < BUCK_SZ) {
        float di = rsqrtf(sdi[t] + 1.0f);   // +1 = self-loop weight
        int node = b * BUCK_SZ + t;
        if (node < N_NODES) dinv[node] = di;
        sdi[t] = di;
    }
    __syncthreads();
    // inclusive scan over 128 counts (all 256 threads hit barriers)
    for (int off = 1; off < BUCK_SZ; off <<= 1) {
        int x = 0;
        if (t < BUCK_SZ && t >= off) x = scnt[t - off];
        __syncthreads();
        if (t < BUCK_SZ) scnt[t] += x;
        __syncthreads();
    }
    if (t < BUCK_SZ) {
        int excl = (t > 0) ? scnt[t - 1] : 0;
        scur[t] = beg + excl;
        int node = b * BUCK_SZ + t;
        if (node < N_NODES) nptr[node] = beg + excl;
    }
    __syncthreads();
    // pass 2: scatter within bucket + w' = w * dinv[c]
    for (int i = t; i < n; i += 256) {
        uint2 u = fit ? se[i] : nt_u2(ebuf + beg + i);
        int r = u.x & 131071;
        int cl = u.x >> 17;
        float nm = __uint_as_float(u.y) * sdi[cl];
        int p = atomicAdd(&scur[cl], 1);
        ebuf2[p] = make_uint2((unsigned)r, __float_as_uint(nm));
    }
}

// ---------------------------------------------------------------------------
// GEMM: out[n][c] = dinv[n] * sum_k in[n][k]*W[k][c]; fp16 output (h' = dinv*h).
// BNH: input is fp16 with fused BN+ReLU (layer 2); else f32 input (layer 1).
template <int K, bool BNH>
__global__ __launch_bounds__(256) void k_gemm(const void* __restrict__ in_,
                                              const float* __restrict__ W,
                                              const float* __restrict__ scale,
                                              const float* __restrict__ shift,
                                              const float* __restrict__ dinv,
                                              _Float16* __restrict__ out) {
    __shared__ float ws[K * 64];
    __shared__ float xs[32 * 132];
    __shared__ float ssc[64], ssh[64];
    int t = threadIdx.x;
    int nbase = blockIdx.x * 128;

#pragma unroll
    for (int i = 0; i < K / 16; ++i) {
        int idx = t + 256 * i;
        ((float4*)ws)[idx] = ((const float4*)W)[idx];
    }
    if (BNH && t < 64) { ssc[t] = scale[t]; ssh[t] = shift[t]; }

    int cg = t & 15;
    int ng = t >> 4;
    float acc[8][4];
#pragma unroll
    for (int i = 0; i < 8; ++i)
#pragma unroll
        for (int j = 0; j < 4; ++j) acc[i][j] = 0.f;

    for (int k0 = 0; k0 < K; k0 += 32) {
        __syncthreads();
#pragma unroll
        for (int i = 0; i < 4; ++i) {
            int idx = t + 256 * i;
            int row = idx >> 3;
            int kq = idx & 7;
            int node = nbase + row;
            float vv[4] = {0.f, 0.f, 0.f, 0.f};
            if (node < N_NODES) {
                if (BNH) {
                    vh4 v = nt_h4((const _Float16*)in_ + (size_t)node * K + k0 + kq * 4);
                    vv[0] = (float)v.x; vv[1] = (float)v.y;
                    vv[2] = (float)v.z; vv[3] = (float)v.w;
                } else {
                    float4 v = nt_f4((const float*)in_ + (size_t)node * K + k0 + kq * 4);
                    vv[0] = v.x; vv[1] = v.y; vv[2] = v.z; vv[3] = v.w;
                }
            }
#pragma unroll
            for (int u = 0; u < 4; ++u) {
                float val = vv[u];
                if (BNH) {
                    int k = k0 + kq * 4 + u;
                    val = fmaxf(ssc[k] * val + ssh[k], 0.f);
                }
                xs[(kq * 4 + u) * 132 + row] = val;
            }
        }
        __syncthreads();
#pragma unroll
        for (int k = 0; k < 32; ++k) {
            float4 wv = *(const float4*)(ws + (k0 + k) * 64 + cg * 4);
            float4 xa = *(const float4*)(xs + k * 132 + ng * 8);
            float4 xb = *(const float4*)(xs + k * 132 + ng * 8 + 4);
            float xv[8] = {xa.x, xa.y, xa.z, xa.w, xb.x, xb.y, xb.z, xb.w};
            float wvv[4] = {wv.x, wv.y, wv.z, wv.w};
#pragma unroll
            for (int i = 0; i < 8; ++i)
#pragma unroll
                for (int j = 0; j < 4; ++j) acc[i][j] += xv[i] * wvv[j];
        }
    }
#pragma unroll
    for (int i = 0; i < 8; ++i) {
        int node = nbase + ng * 8 + i;
        if (node < N_NODES) {
            float dv = dinv[node];
            vh4 o;
            o.x = (_Float16)(acc[i][0] * dv); o.y = (_Float16)(acc[i][1] * dv);
            o.z = (_Float16)(acc[i][2] * dv); o.w = (_Float16)(acc[i][3] * dv);
            *(vh4*)(out + (size_t)node * 64 + cg * 4) = o;
        }
    }
}

// ---------------------------------------------------------------------------
// CSR gather-aggregation: block stages its 32 nodes' contiguous edge metas in
// LDS (one coalesced pass); per-edge path is ds_read -> independent row gather.
// hin is dinv-scaled (h'), edges carry w' = w*dinv[c]:
//   out[v] = sum w'*h'[r] + dinv[v]*h'[v] + bias   (== GCN layer exactly)
__global__ __launch_bounds__(256) void k_agg(const _Float16* __restrict__ hin,
                                             const uint2* __restrict__ ebuf2,
                                             const int* __restrict__ nptr,
                                             const float* __restrict__ dinv,
                                             const float* __restrict__ bias,
                                             _Float16* __restrict__ hout,
                                             float* __restrict__ bn_shard) {
    __shared__ uint2 sme[AGG_CAP];
    __shared__ float sm[4][64], qm[4][64];
    int b = blockIdx.x, t = threadIdx.x;
    int wave = t >> 6, lane = t & 63;
    int vbase0 = b * 32;                       // grid is exactly N_NODES/32
    int ebeg = nptr[vbase0];
    int eend = nptr[vbase0 + 32];
    int n = eend - ebeg;
    bool fit = (n <= AGG_CAP);
    if (fit) {
        for (int i = t; i < n; i += 256) sme[i] = nt_u2(ebuf2 + ebeg + i);
    }
    __syncthreads();

    float s = 0.f, q = 0.f;
    float bl = bias[lane];
    int vbase = vbase0 + wave * 8;
    for (int vi = 0; vi < 8; ++vi) {
        int v = vbase + vi;
        int beg = nptr[v], end = nptr[v + 1];
        float acc = 0.f;
        int j = beg;
        if (fit) {
            for (; j + 8 <= end; j += 8) {
                float fv[8], fn[8];
#pragma unroll
                for (int u = 0; u < 8; ++u) {
                    uint2 e = sme[j - ebeg + u];
                    fn[u] = __uint_as_float(e.y);
                    fv[u] = (float)hin[((size_t)e.x << 6) + lane];
                }
#pragma unroll
                for (int u = 0; u < 8; ++u) acc = fmaf(fn[u], fv[u], acc);
            }
            for (; j < end; ++j) {
                uint2 e = sme[j - ebeg];
                acc = fmaf(__uint_as_float(e.y),
                           (float)hin[((size_t)e.x << 6) + lane], acc);
            }
        } else {
            for (; j + 8 <= end; j += 8) {
                float fv[8], fn[8];
#pragma unroll
                for (int u = 0; u < 8; ++u) {
                    uint2 e = nt_u2(ebuf2 + j + u);
                    fn[u] = __uint_as_float(e.y);
                    fv[u] = (float)hin[((size_t)e.x << 6) + lane];
                }
#pragma unroll
                for (int u = 0; u < 8; ++u) acc = fmaf(fn[u], fv[u], acc);
            }
            for (; j < end; ++j) {
                uint2 e = nt_u2(ebuf2 + j);
                acc = fmaf(__uint_as_float(e.y),
                           (float)hin[((size_t)e.x << 6) + lane], acc);
            }
        }
        float dv = dinv[v];
        acc = fmaf(dv, (float)hin[((size_t)v << 6) + lane], acc);  // dinv*h' = dinv^2*h
        acc += bl;
        hout[((size_t)v << 6) + lane] = (_Float16)acc;
        s += acc;
        q += acc * acc;
    }
    sm[wave][lane] = s;
    qm[wave][lane] = q;
    __syncthreads();
    if (wave == 0) {
        float ts = sm[0][lane] + sm[1][lane] + sm[2][lane] + sm[3][lane];
        float tq = qm[0][lane] + qm[1][lane] + qm[2][lane] + qm[3][lane];
        float* shard = bn_shard + (blockIdx.x & (NSHARD - 1)) * 128;
        atomicAdd(&shard[lane], ts);
        atomicAdd(&shard[64 + lane], tq);
    }
}

// reduce BN shards -> scale/shift; re-zero shards for the next layer
__global__ void k_bn_final(float* __restrict__ bn_shard, const float* __restrict__ gamma,
                           const float* __restrict__ beta, float* __restrict__ scale,
                           float* __restrict__ shift) {
    int t = threadIdx.x;
    if (t < 64) {
        float s = 0.f, q = 0.f;
        for (int i = 0; i < NSHARD; ++i) {
            s += bn_shard[i * 128 + t];
            q += bn_shard[i * 128 + 64 + t];
        }
        float mean = s * (1.0f / N_NODES);
        float var = q * (1.0f / N_NODES) - mean * mean;
        float sc = gamma[t] * rsqrtf(var + BN_EPS);
        scale[t] = sc;
        shift[t] = beta[t] - mean * sc;
    }
    __syncthreads();
    for (int i = t; i < NSHARD * 128; i += 256) bn_shard[i] = 0.f;
}

// ---------------------------------------------------------------------------
// pool: 782 blocks x 128 rows, sharded accumulators (blockIdx&15, XCD-local)
__global__ __launch_bounds__(256) void k_pool(const _Float16* __restrict__ a2,
                                              const float* __restrict__ scale,
                                              const float* __restrict__ shift,
                                              const int* __restrict__ batch,
                                              float* __restrict__ pooled_sh,
                                              float* __restrict__ pcnt_sh) {
    int b = blockIdx.x, t = threadIdx.x;
    int c = t & 63;
    int rg = t >> 6;
    int base = b * BUCK_SZ;
    float sc = scale[c], sh = shift[c];
    float* pool_s = pooled_sh + (size_t)(b & (NSHARD - 1)) * (N_GRAPHS * 64);
    float* pcnt_s = pcnt_sh + (size_t)(b & (NSHARD - 1)) * N_GRAPHS;
    int gcur = -1;
    float acc = 0.f, cacc = 0.f;
    for (int i = rg; i < BUCK_SZ; i += 4) {
        int v = base + i;
        if (v >= N_NODES) break;
        int g = batch[v];
        if (g != gcur) {
            if (gcur >= 0) {
                atomicAdd(&pool_s[gcur * 64 + c], acc);
                if (c == 0) atomicAdd(&pcnt_s[gcur], cacc);
            }
            gcur = g;
            acc = 0.f;
            cacc = 0.f;
        }
        float h = fmaxf(sc * (float)a2[(size_t)v * 64 + c] + sh, 0.f);
        acc += h;
        cacc += 1.f;
    }
    if (gcur >= 0) {
        atomicAdd(&pool_s[gcur * 64 + c], acc);
        if (c == 0) atomicAdd(&pcnt_s[gcur], cacc);
    }
}

__global__ void k_out(const float* __restrict__ pooled_sh,
                      const float* __restrict__ pcnt_sh,
                      const float* __restrict__ Wout, const float* __restrict__ bout,
                      float* __restrict__ out) {
    int g = threadIdx.x;
    if (g < N_GRAPHS) {
        float cnt = 0.f;
        for (int s = 0; s < NSHARD; ++s) cnt += pcnt_sh[s * N_GRAPHS + g];
        cnt = fmaxf(cnt, 1.0f);
        float sum = 0.f;
        for (int c = 0; c < 64; ++c) {
            float p = 0.f;
            for (int s = 0; s < NSHARD; ++s)
                p += pooled_sh[(size_t)s * N_GRAPHS * 64 + g * 64 + c];
            sum += p * Wout[c];
        }
        out[g] = sum / cnt + bout[0];
    }
}

// ---------------------------------------------------------------------------
extern "C" void kernel_launch(void* const* d_in, const int* in_sizes, int n_in,
                              void* d_out, int out_size, void* d_ws, size_t ws_size,
                              hipStream_t stream) {
    const float* x    = (const float*)d_in[0];
    const int*   ei   = (const int*)d_in[1];
    const float* ew   = (const float*)d_in[2];
    const int*   batch= (const int*)d_in[3];
    const float* W1   = (const float*)d_in[4];
    const float* b1   = (const float*)d_in[5];
    const float* W2   = (const float*)d_in[6];
    const float* b2   = (const float*)d_in[7];
    const float* g1   = (const float*)d_in[8];
    const float* be1  = (const float*)d_in[9];
    const float* g2   = (const float*)d_in[10];
    const float* be2  = (const float*)d_in[11];
    const float* Wout = (const float*)d_in[12];
    const float* bout = (const float*)d_in[13];
    float* out = (float*)d_out;

    char* w = (char*)d_ws;
    size_t o = 0;
    auto alloc = [&](size_t bytes) -> void* {
        void* p = w + o;
        o = (o + bytes + 255) & ~(size_t)255;
        return p;
    };
    int*   cnt2    = (int*)alloc(NCNT * 4);
    int*   soff    = (int*)alloc((NCNT + 1) * 4);
    int*   cur     = (int*)alloc(NCNT * 4);
    int*   nptr    = (int*)alloc((N_NODES + 1) * 4);
    float* dinv    = (float*)alloc(N_NODES * 4);
    float* bnshard = (float*)alloc(NSHARD * 128 * 4);
    float* scale1  = (float*)alloc(64 * 4);
    float* shift1  = (float*)alloc(64 * 4);
    float* scale2  = (float*)alloc(64 * 4);
    float* shift2  = (float*)alloc(64 * 4);
    float* pooled  = (float*)alloc(NSHARD * N_GRAPHS * 64 * 4);
    float* pcnt    = (float*)alloc(NSHARD * N_GRAPHS * 4);
    uint2* ebuf2   = (uint2*)alloc((size_t)N_EDGES * 8);
    // 25.6 MB region triple-use: ebuf (binning scratch, dead after k_sortnorm)
    // then two fp16 node buffers HA/HB (12.8 MB each), written only after.
    uint2* ebuf    = (uint2*)alloc((size_t)N_EDGES * 8);
    _Float16* bufHA = (_Float16*)ebuf;
    _Float16* bufHB = bufHA + (size_t)N_NODES * 64;
    if (o > ws_size) return;

    (void)hipMemsetAsync(cnt2, 0, NCNT * 4, stream);
    (void)hipMemsetAsync(bnshard, 0, NSHARD * 128 * 4, stream);
    (void)hipMemsetAsync(pooled, 0, NSHARD * N_GRAPHS * 64 * 4, stream);
    (void)hipMemsetAsync(pcnt, 0, NSHARD * N_GRAPHS * 4, stream);

    k_count<<<BIN_BLOCKS, 256, 0, stream>>>(ei, cnt2);
    k_scan6k<<<1, 256, 0, stream>>>(cnt2, soff, cur, nptr);
    k_bin<<<BIN_BLOCKS, 256, 0, stream>>>(ei, ew, cur, ebuf);
    k_sortnorm<<<NBUCK, 256, 0, stream>>>(ebuf, soff, dinv, ebuf2, nptr);

    // layer 1: x (f32) -> h1' = dinv*(x@W1) (fp16) -> a1 (fp16) + BN1 stats
    k_gemm<128, false><<<(N_NODES + 127) / 128, 256, 0, stream>>>(x, W1, nullptr, nullptr, dinv, bufHA);
    k_agg<<<N_NODES / 32, 256, 0, stream>>>(bufHA, ebuf2, nptr, dinv, b1, bufHB, bnshard);
    k_bn_final<<<1, 256, 0, stream>>>(bnshard, g1, be1, scale1, shift1);

    // layer 2: a1 (fp16, fused BN+ReLU) -> h2' (fp16) -> a2 (fp16) + BN2 stats
    k_gemm<64, true><<<(N_NODES + 127) / 128, 256, 0, stream>>>(bufHB, W2, scale1, shift1, dinv, bufHA);
    k_agg<<<N_NODES / 32, 256, 0, stream>>>(bufHA, ebuf2, nptr, dinv, b2, bufHB, bnshard);
    k_bn_final<<<1, 256, 0, stream>>>(bnshard, g2, be2, scale2, shift2);

    // pool (fused BN2+ReLU, sharded accumulators) + output
    k_pool<<<NBUCK, 256, 0, stream>>>(bufHB, scale2, shift2, batch, pooled, pcnt);
    k_out<<<1, 64, 0, stream>>>(pooled, pcnt, Wout, bout, out);
}

// Round 13
// 379.652 us; speedup vs baseline: 2.7785x; 1.1266x over previous
//
#include <hip/hip_runtime.h>
#include <stdint.h>

#define N_NODES 100000
#define N_EDGES 3200000
#define IN_DIM 128
#define HID 64
#define N_GRAPHS 64
#define BN_EPS 1e-5f
#define NSHARD 16
#define BUCK_SH 7
#define BUCK_SZ 128
#define NBUCK ((N_NODES + BUCK_SZ - 1) / BUCK_SZ)   // 782
#define NCNT (NBUCK * 8)                             // 6256
#define BINB_EDGES 4096                              // edges per binning block
#define BIN_BLOCKS ((N_EDGES + BINB_EDGES - 1) / BINB_EDGES)  // 782
#define SLOT_CAP 768                                 // per-(bucket,stream) ebuf slot (mean 512, +11 sigma)
#define BCAP 4608                                    // per-bucket ebuf2 region (mean 4092, +8 sigma)
#define SORT_CAP (8 * SLOT_CAP)                      // 6144, always fits staged bucket
#define AGG_CAP 2048                                 // agg block edge stage (mean 1024)

// __builtin_nontemporal_load needs native (ext_vector) types, not HIP structs.
typedef float vf4 __attribute__((ext_vector_type(4)));
typedef int   vi4 __attribute__((ext_vector_type(4)));
typedef unsigned vu2 __attribute__((ext_vector_type(2)));
typedef _Float16 vh4 __attribute__((ext_vector_type(4)));

__device__ __forceinline__ float4 nt_f4(const float* p) {
    vf4 v = __builtin_nontemporal_load((const vf4*)p);
    return make_float4(v.x, v.y, v.z, v.w);
}
__device__ __forceinline__ int4 nt_i4(const int* p) {
    vi4 v = __builtin_nontemporal_load((const vi4*)p);
    return make_int4(v.x, v.y, v.z, v.w);
}
__device__ __forceinline__ uint2 nt_u2(const uint2* p) {
    vu2 v = __builtin_nontemporal_load((const vu2*)p);
    return make_uint2(v.x, v.y);
}
__device__ __forceinline__ vh4 nt_h4(const _Float16* p) {
    return __builtin_nontemporal_load((const vh4*)p);
}

// ---------------------------------------------------------------------------
// init per-(bucket,stream) cursors to fixed slot bases (replaces count+scan)
__global__ void k_init(int* __restrict__ cur) {
    int i = blockIdx.x * blockDim.x + threadIdx.x;
    if (i < NCNT) cur[i] = i * SLOT_CAP;
}

// block-aggregated bin into fixed-capacity slots: stage 4096 edges in LDS,
// LDS histogram, ONE global atomic per non-empty (bucket, s=b&7 XCD-local),
// scatter from LDS. No precomputed offsets needed (slot bases are fixed).
__global__ __launch_bounds__(256) void k_bin(const int* __restrict__ ei,
                                             const float* __restrict__ ew,
                                             int* __restrict__ cur,
                                             uint2* __restrict__ ebuf) {
    __shared__ uint2 sed[BINB_EDGES];
    __shared__ unsigned short sbk[BINB_EDGES];
    __shared__ int hist[NBUCK];
    int b = blockIdx.x, t = threadIdx.x;
    int s = b & 7;
    int base = b * BINB_EDGES;
    int n = min(BINB_EDGES, N_EDGES - base);
    for (int i = t; i < NBUCK; i += 256) hist[i] = 0;
    __syncthreads();
#pragma unroll
    for (int k = 0; k < 4; ++k) {
        int ch = t + 256 * k;
        if (4 * ch < n) {
            int4 r4 = nt_i4(ei + base + 4 * ch);
            int4 c4 = nt_i4(ei + N_EDGES + base + 4 * ch);
            float4 w4 = nt_f4(ew + base + 4 * ch);
            int rr[4] = {r4.x, r4.y, r4.z, r4.w};
            int cc[4] = {c4.x, c4.y, c4.z, c4.w};
            float ww[4] = {w4.x, w4.y, w4.z, w4.w};
#pragma unroll
            for (int u = 0; u < 4; ++u) {
                int li = 4 * ch + u;
                sed[li] = make_uint2(
                    (unsigned)(rr[u] | ((cc[u] & (BUCK_SZ - 1)) << 17)),
                    __float_as_uint(ww[u]));
                int bk = cc[u] >> BUCK_SH;
                sbk[li] = (unsigned short)bk;
                atomicAdd(&hist[bk], 1);
            }
        }
    }
    __syncthreads();
    for (int j = t; j < NBUCK; j += 256) {
        int h = hist[j];
        if (h > 0) hist[j] = atomicAdd(&cur[(j << 3) + s], h);
    }
    __syncthreads();
    for (int i = t; i < n; i += 256) {
        int bk = sbk[i];
        int pos = atomicAdd(&hist[bk], 1);
        ebuf[pos] = sed[i];
    }
}

// ---------------------------------------------------------------------------
// fused prep (dinv-factorized, slotted input): per bucket, read the 8 slots
// (lengths from cursors), stage in LDS, compute weighted degree -> dinv[c]
// (bucket-LOCAL, no cross-block race), dest histogram -> per-node ranges,
// scatter compacted into ebuf2[b*BCAP ...] with w' = w * dinv[c].
// nrange[v] = {beg, end} (exact, gap-free within bucket).
__global__ __launch_bounds__(256) void k_sortnorm(const uint2* __restrict__ ebuf,
                                                  const int* __restrict__ cur,
                                                  float* __restrict__ dinv,
                                                  uint2* __restrict__ ebuf2,
                                                  int2* __restrict__ nrange) {
    __shared__ uint2 se[SORT_CAP];
    __shared__ float sdi[BUCK_SZ];   // degree accum, then dinv
    __shared__ int scnt[BUCK_SZ];
    __shared__ int scur[BUCK_SZ];
    __shared__ int slen[8], soffc[8];
    int b = blockIdx.x, t = threadIdx.x;
    if (t < BUCK_SZ) { sdi[t] = 0.f; scnt[t] = 0; }
    if (t < 8) slen[t] = cur[(b << 3) + t] - ((b << 3) + t) * SLOT_CAP;
    __syncthreads();
    if (t == 0) {
        int run = 0;
#pragma unroll
        for (int s = 0; s < 8; ++s) { soffc[s] = run; run += slen[s]; }
    }
    __syncthreads();
    // pass 1: stage all 8 segments compactly + weighted degree + histogram
    for (int s = 0; s < 8; ++s) {
        int sb = ((b << 3) + s) * SLOT_CAP;
        int len = slen[s];
        int off = soffc[s];
        for (int i = t; i < len; i += 256) {
            uint2 u = nt_u2(ebuf + sb + i);
            se[off + i] = u;
            int cl = u.x >> 17;
            atomicAdd(&sdi[cl], __uint_as_float(u.y));
            atomicAdd(&scnt[cl], 1);
        }
    }
    __syncthreads();
    int n = soffc[7] + slen[7];
    if (t < BUCK_SZ) {
        float di = rsqrtf(sdi[t] + 1.0f);   // +1 = self-loop weight
        int node = b * BUCK_SZ + t;
        if (node < N_NODES) dinv[node] = di;
        sdi[t] = di;
    }
    __syncthreads();
    // inclusive scan over 128 counts (all 256 threads hit barriers)
    for (int off = 1; off < BUCK_SZ; off <<= 1) {
        int x = 0;
        if (t < BUCK_SZ && t >= off) x = scnt[t - off];
        __syncthreads();
        if (t < BUCK_SZ) scnt[t] += x;
        __syncthreads();
    }
    if (t < BUCK_SZ) {
        int excl = (t > 0) ? scnt[t - 1] : 0;
        int cnt = scnt[t] - excl;
        scur[t] = b * BCAP + excl;
        int node = b * BUCK_SZ + t;
        if (node < N_NODES) nrange[node] = make_int2(b * BCAP + excl, b * BCAP + excl + cnt);
    }
    __syncthreads();
    // pass 2: scatter within bucket + w' = w * dinv[c]
    for (int i = t; i < n; i += 256) {
        uint2 u = se[i];
        int r = u.x & 131071;
        int cl = u.x >> 17;
        float nm = __uint_as_float(u.y) * sdi[cl];
        int p = atomicAdd(&scur[cl], 1);
        ebuf2[p] = make_uint2((unsigned)r, __float_as_uint(nm));
    }
}

// ---------------------------------------------------------------------------
// GEMM: out[n][c] = dinv[n] * sum_k in[n][k]*W[k][c]; fp16 output (h' = dinv*h).
// BNH: input is fp16 with fused BN+ReLU (layer 2); else f32 input (layer 1).
template <int K, bool BNH>
__global__ __launch_bounds__(256) void k_gemm(const void* __restrict__ in_,
                                              const float* __restrict__ W,
                                              const float* __restrict__ scale,
                                              const float* __restrict__ shift,
                                              const float* __restrict__ dinv,
                                              _Float16* __restrict__ out) {
    __shared__ float ws[K * 64];
    __shared__ float xs[32 * 132];
    __shared__ float ssc[64], ssh[64];
    int t = threadIdx.x;
    int nbase = blockIdx.x * 128;

#pragma unroll
    for (int i = 0; i < K / 16; ++i) {
        int idx = t + 256 * i;
        ((float4*)ws)[idx] = ((const float4*)W)[idx];
    }
    if (BNH && t < 64) { ssc[t] = scale[t]; ssh[t] = shift[t]; }

    int cg = t & 15;
    int ng = t >> 4;
    float acc[8][4];
#pragma unroll
    for (int i = 0; i < 8; ++i)
#pragma unroll
        for (int j = 0; j < 4; ++j) acc[i][j] = 0.f;

    for (int k0 = 0; k0 < K; k0 += 32) {
        __syncthreads();
#pragma unroll
        for (int i = 0; i < 4; ++i) {
            int idx = t + 256 * i;
            int row = idx >> 3;
            int kq = idx & 7;
            int node = nbase + row;
            float vv[4] = {0.f, 0.f, 0.f, 0.f};
            if (node < N_NODES) {
                if (BNH) {
                    vh4 v = nt_h4((const _Float16*)in_ + (size_t)node * K + k0 + kq * 4);
                    vv[0] = (float)v.x; vv[1] = (float)v.y;
                    vv[2] = (float)v.z; vv[3] = (float)v.w;
                } else {
                    float4 v = nt_f4((const float*)in_ + (size_t)node * K + k0 + kq * 4);
                    vv[0] = v.x; vv[1] = v.y; vv[2] = v.z; vv[3] = v.w;
                }
            }
#pragma unroll
            for (int u = 0; u < 4; ++u) {
                float val = vv[u];
                if (BNH) {
                    int k = k0 + kq * 4 + u;
                    val = fmaxf(ssc[k] * val + ssh[k], 0.f);
                }
                xs[(kq * 4 + u) * 132 + row] = val;
            }
        }
        __syncthreads();
#pragma unroll
        for (int k = 0; k < 32; ++k) {
            float4 wv = *(const float4*)(ws + (k0 + k) * 64 + cg * 4);
            float4 xa = *(const float4*)(xs + k * 132 + ng * 8);
            float4 xb = *(const float4*)(xs + k * 132 + ng * 8 + 4);
            float xv[8] = {xa.x, xa.y, xa.z, xa.w, xb.x, xb.y, xb.z, xb.w};
            float wvv[4] = {wv.x, wv.y, wv.z, wv.w};
#pragma unroll
            for (int i = 0; i < 8; ++i)
#pragma unroll
                for (int j = 0; j < 4; ++j) acc[i][j] += xv[i] * wvv[j];
        }
    }
#pragma unroll
    for (int i = 0; i < 8; ++i) {
        int node = nbase + ng * 8 + i;
        if (node < N_NODES) {
            float dv = dinv[node];
            vh4 o;
            o.x = (_Float16)(acc[i][0] * dv); o.y = (_Float16)(acc[i][1] * dv);
            o.z = (_Float16)(acc[i][2] * dv); o.w = (_Float16)(acc[i][3] * dv);
            *(vh4*)(out + (size_t)node * 64 + cg * 4) = o;
        }
    }
}

// ---------------------------------------------------------------------------
// CSR gather-aggregation: block stages its 32 nodes' contiguous edge metas in
// LDS; per-edge path is ds_read -> independent row gather, 16-deep pipelined.
//   out[v] = sum w'*h'[r] + dinv[v]*h'[v] + bias   (== GCN layer exactly)
__global__ __launch_bounds__(256) void k_agg(const _Float16* __restrict__ hin,
                                             const uint2* __restrict__ ebuf2,
                                             const int2* __restrict__ nrange,
                                             const float* __restrict__ dinv,
                                             const float* __restrict__ bias,
                                             _Float16* __restrict__ hout,
                                             float* __restrict__ bn_shard) {
    __shared__ uint2 sme[AGG_CAP];
    __shared__ float sm[4][64], qm[4][64];
    int b = blockIdx.x, t = threadIdx.x;
    int wave = t >> 6, lane = t & 63;
    int vbase0 = b * 32;                       // grid is exactly N_NODES/32
    int ebeg = nrange[vbase0].x;
    int eend = nrange[vbase0 + 31].y;
    int n = eend - ebeg;
    bool fit = (n <= AGG_CAP);
    if (fit) {
        for (int i = t; i < n; i += 256) sme[i] = nt_u2(ebuf2 + ebeg + i);
    }
    __syncthreads();

    float s = 0.f, q = 0.f;
    float bl = bias[lane];
    int vbase = vbase0 + wave * 8;
    for (int vi = 0; vi < 8; ++vi) {
        int v = vbase + vi;
        int2 be = nrange[v];
        int beg = be.x, end = be.y;
        float acc = 0.f;
        int j = beg;
        if (fit) {
            for (; j + 16 <= end; j += 16) {
                float fv[16], fn[16];
#pragma unroll
                for (int u = 0; u < 16; ++u) {
                    uint2 e = sme[j - ebeg + u];
                    fn[u] = __uint_as_float(e.y);
                    fv[u] = (float)hin[((size_t)e.x << 6) + lane];
                }
#pragma unroll
                for (int u = 0; u < 16; ++u) acc = fmaf(fn[u], fv[u], acc);
            }
            for (; j + 8 <= end; j += 8) {
                float fv[8], fn[8];
#pragma unroll
                for (int u = 0; u < 8; ++u) {
                    uint2 e = sme[j - ebeg + u];
                    fn[u] = __uint_as_float(e.y);
                    fv[u] = (float)hin[((size_t)e.x << 6) + lane];
                }
#pragma unroll
                for (int u = 0; u < 8; ++u) acc = fmaf(fn[u], fv[u], acc);
            }
            for (; j < end; ++j) {
                uint2 e = sme[j - ebeg];
                acc = fmaf(__uint_as_float(e.y),
                           (float)hin[((size_t)e.x << 6) + lane], acc);
            }
        } else {
            for (; j + 8 <= end; j += 8) {
                float fv[8], fn[8];
#pragma unroll
                for (int u = 0; u < 8; ++u) {
                    uint2 e = nt_u2(ebuf2 + j + u);
                    fn[u] = __uint_as_float(e.y);
                    fv[u] = (float)hin[((size_t)e.x << 6) + lane];
                }
#pragma unroll
                for (int u = 0; u < 8; ++u) acc = fmaf(fn[u], fv[u], acc);
            }
            for (; j < end; ++j) {
                uint2 e = nt_u2(ebuf2 + j);
                acc = fmaf(__uint_as_float(e.y),
                           (float)hin[((size_t)e.x << 6) + lane], acc);
            }
        }
        float dv = dinv[v];
        acc = fmaf(dv, (float)hin[((size_t)v << 6) + lane], acc);  // dinv*h' = dinv^2*h
        acc += bl;
        hout[((size_t)v << 6) + lane] = (_Float16)acc;
        s += acc;
        q += acc * acc;
    }
    sm[wave][lane] = s;
    qm[wave][lane] = q;
    __syncthreads();
    if (wave == 0) {
        float ts = sm[0][lane] + sm[1][lane] + sm[2][lane] + sm[3][lane];
        float tq = qm[0][lane] + qm[1][lane] + qm[2][lane] + qm[3][lane];
        float* shard = bn_shard + (blockIdx.x & (NSHARD - 1)) * 128;
        atomicAdd(&shard[lane], ts);
        atomicAdd(&shard[64 + lane], tq);
    }
}

// reduce BN shards -> scale/shift; re-zero shards for the next layer
__global__ void k_bn_final(float* __restrict__ bn_shard, const float* __restrict__ gamma,
                           const float* __restrict__ beta, float* __restrict__ scale,
                           float* __restrict__ shift) {
    int t = threadIdx.x;
    if (t < 64) {
        float s = 0.f, q = 0.f;
        for (int i = 0; i < NSHARD; ++i) {
            s += bn_shard[i * 128 + t];
            q += bn_shard[i * 128 + 64 + t];
        }
        float mean = s * (1.0f / N_NODES);
        float var = q * (1.0f / N_NODES) - mean * mean;
        float sc = gamma[t] * rsqrtf(var + BN_EPS);
        scale[t] = sc;
        shift[t] = beta[t] - mean * sc;
    }
    __syncthreads();
    for (int i = t; i < NSHARD * 128; i += 256) bn_shard[i] = 0.f;
}

// ---------------------------------------------------------------------------
// pool: 782 blocks x 128 rows, sharded accumulators (blockIdx&15, XCD-local)
__global__ __launch_bounds__(256) void k_pool(const _Float16* __restrict__ a2,
                                              const float* __restrict__ scale,
                                              const float* __restrict__ shift,
                                              const int* __restrict__ batch,
                                              float* __restrict__ pooled_sh,
                                              float* __restrict__ pcnt_sh) {
    int b = blockIdx.x, t = threadIdx.x;
    int c = t & 63;
    int rg = t >> 6;
    int base = b * BUCK_SZ;
    float sc = scale[c], sh = shift[c];
    float* pool_s = pooled_sh + (size_t)(b & (NSHARD - 1)) * (N_GRAPHS * 64);
    float* pcnt_s = pcnt_sh + (size_t)(b & (NSHARD - 1)) * N_GRAPHS;
    int gcur = -1;
    float acc = 0.f, cacc = 0.f;
    for (int i = rg; i < BUCK_SZ; i += 4) {
        int v = base + i;
        if (v >= N_NODES) break;
        int g = batch[v];
        if (g != gcur) {
            if (gcur >= 0) {
                atomicAdd(&pool_s[gcur * 64 + c], acc);
                if (c == 0) atomicAdd(&pcnt_s[gcur], cacc);
            }
            gcur = g;
            acc = 0.f;
            cacc = 0.f;
        }
        float h = fmaxf(sc * (float)a2[(size_t)v * 64 + c] + sh, 0.f);
        acc += h;
        cacc += 1.f;
    }
    if (gcur >= 0) {
        atomicAdd(&pool_s[gcur * 64 + c], acc);
        if (c == 0) atomicAdd(&pcnt_s[gcur], cacc);
    }
}

__global__ void k_out(const float* __restrict__ pooled_sh,
                      const float* __restrict__ pcnt_sh,
                      const float* __restrict__ Wout, const float* __restrict__ bout,
                      float* __restrict__ out) {
    int g = threadIdx.x;
    if (g < N_GRAPHS) {
        float cnt = 0.f;
        for (int s = 0; s < NSHARD; ++s) cnt += pcnt_sh[s * N_GRAPHS + g];
        cnt = fmaxf(cnt, 1.0f);
        float sum = 0.f;
        for (int c = 0; c < 64; ++c) {
            float p = 0.f;
            for (int s = 0; s < NSHARD; ++s)
                p += pooled_sh[(size_t)s * N_GRAPHS * 64 + g * 64 + c];
            sum += p * Wout[c];
        }
        out[g] = sum / cnt + bout[0];
    }
}

// ---------------------------------------------------------------------------
extern "C" void kernel_launch(void* const* d_in, const int* in_sizes, int n_in,
                              void* d_out, int out_size, void* d_ws, size_t ws_size,
                              hipStream_t stream) {
    const float* x    = (const float*)d_in[0];
    const int*   ei   = (const int*)d_in[1];
    const float* ew   = (const float*)d_in[2];
    const int*   batch= (const int*)d_in[3];
    const float* W1   = (const float*)d_in[4];
    const float* b1   = (const float*)d_in[5];
    const float* W2   = (const float*)d_in[6];
    const float* b2   = (const float*)d_in[7];
    const float* g1   = (const float*)d_in[8];
    const float* be1  = (const float*)d_in[9];
    const float* g2   = (const float*)d_in[10];
    const float* be2  = (const float*)d_in[11];
    const float* Wout = (const float*)d_in[12];
    const float* bout = (const float*)d_in[13];
    float* out = (float*)d_out;

    char* w = (char*)d_ws;
    size_t o = 0;
    auto alloc = [&](size_t bytes) -> void* {
        void* p = w + o;
        o = (o + bytes + 255) & ~(size_t)255;
        return p;
    };
    int*   cur     = (int*)alloc(NCNT * 4);
    int2*  nrange  = (int2*)alloc((size_t)N_NODES * 8);
    float* dinv    = (float*)alloc(N_NODES * 4);
    float* bnshard = (float*)alloc(NSHARD * 128 * 4);
    float* scale1  = (float*)alloc(64 * 4);
    float* shift1  = (float*)alloc(64 * 4);
    float* scale2  = (float*)alloc(64 * 4);
    float* shift2  = (float*)alloc(64 * 4);
    float* pooled  = (float*)alloc(NSHARD * N_GRAPHS * 64 * 4);
    float* pcnt    = (float*)alloc(NSHARD * N_GRAPHS * 4);
    uint2* ebuf2   = (uint2*)alloc((size_t)NBUCK * BCAP * 8);     // 28.8 MB
    // 38.4 MB region double-use: ebuf (slotted binning scratch, dead after
    // k_sortnorm), then two fp16 node buffers HA/HB (12.8 MB each).
    uint2* ebuf    = (uint2*)alloc((size_t)NCNT * SLOT_CAP * 8);  // 38.4 MB
    _Float16* bufHA = (_Float16*)ebuf;
    _Float16* bufHB = bufHA + (size_t)N_NODES * 64;
    if (o > ws_size) return;

    (void)hipMemsetAsync(bnshard, 0, NSHARD * 128 * 4, stream);
    (void)hipMemsetAsync(pooled, 0, NSHARD * N_GRAPHS * 64 * 4, stream);
    (void)hipMemsetAsync(pcnt, 0, NSHARD * N_GRAPHS * 4, stream);

    k_init<<<(NCNT + 255) / 256, 256, 0, stream>>>(cur);
    k_bin<<<BIN_BLOCKS, 256, 0, stream>>>(ei, ew, cur, ebuf);
    k_sortnorm<<<NBUCK, 256, 0, stream>>>(ebuf, cur, dinv, ebuf2, nrange);

    // layer 1: x (f32) -> h1' = dinv*(x@W1) (fp16) -> a1 (fp16) + BN1 stats
    k_gemm<128, false><<<(N_NODES + 127) / 128, 256, 0, stream>>>(x, W1, nullptr, nullptr, dinv, bufHA);
    k_agg<<<N_NODES / 32, 256, 0, stream>>>(bufHA, ebuf2, nrange, dinv, b1, bufHB, bnshard);
    k_bn_final<<<1, 256, 0, stream>>>(bnshard, g1, be1, scale1, shift1);

    // layer 2: a1 (fp16, fused BN+ReLU) -> h2' (fp16) -> a2 (fp16) + BN2 stats
    k_gemm<64, true><<<(N_NODES + 127) / 128, 256, 0, stream>>>(bufHB, W2, scale1, shift1, dinv, bufHA);
    k_agg<<<N_NODES / 32, 256, 0, stream>>>(bufHA, ebuf2, nrange, dinv, b2, bufHB, bnshard);
    k_bn_final<<<1, 256, 0, stream>>>(bnshard, g2, be2, scale2, shift2);

    // pool (fused BN2+ReLU, sharded accumulators) + output
    k_pool<<<NBUCK, 256, 0, stream>>>(bufHB, scale2, shift2, batch, pooled, pcnt);
    k_out<<<1, 64, 0, stream>>>(pooled, pcnt, Wout, bout, out);
}